// Round 1
// baseline (4692.236 us; speedup 1.0000x reference)
//
#include <hip/hip_runtime.h>
#include <cstdint>
#include <cstddef>

#define NPTS 4096
#define BATCH 8
#define KNB 20

__device__ __forceinline__ float leaky(float v) { return v > 0.f ? v : 0.2f * v; }

__device__ __forceinline__ unsigned encf(float f) {
  unsigned u = __float_as_uint(f);
  return (u & 0x80000000u) ? ~u : (u | 0x80000000u);
}
__device__ __forceinline__ float decf(unsigned e) {
  unsigned u = (e & 0x80000000u) ? (e & 0x7FFFFFFFu) : ~e;
  return __uint_as_float(u);
}

// key = (~sortable(pd)) << 32 | j : smallest key = largest pd, ties -> smallest j
__device__ __forceinline__ unsigned long long mkkey(float pd, int j) {
  unsigned s = encf(pd);
  return (((unsigned long long)(~s)) << 32) | (unsigned)j;
}

// sorted ascending insert (keeps 20 smallest keys); fully static indexing
__device__ __forceinline__ void heap_insert(unsigned long long (&h)[KNB], unsigned long long key) {
  if (key < h[KNB - 1]) {
    unsigned long long c = key;
#pragma unroll
    for (int t = 0; t < KNB; ++t) {
      unsigned long long o = h[t];
      bool lt = c < o;
      unsigned long long lo = lt ? c : o;
      unsigned long long hi = lt ? o : c;
      h[t] = lo;
      c = hi;
    }
  }
}

// ---------------- kNN on 3-d input points (x is (B,3,N)) ----------------
__global__ __launch_bounds__(256) void knn_c3(const float* __restrict__ x, int* __restrict__ idxo) {
  __shared__ float sx[NPTS], sy[NPTS], sz[NPTS];
  int b = blockIdx.y, tid = threadIdx.x;
  const float* xb = x + (size_t)b * 3 * NPTS;
#pragma unroll
  for (int l = 0; l < NPTS / 256; ++l) {
    int t = tid + l * 256;
    sx[t] = xb[t];
    sy[t] = xb[NPTS + t];
    sz[t] = xb[2 * NPTS + t];
  }
  __syncthreads();
  int i = blockIdx.x * 256 + tid;
  float qx = sx[i], qy = sy[i], qz = sz[i];
  float qn = fmaf(qz, qz, fmaf(qy, qy, qx * qx));
  unsigned long long h[KNB];
#pragma unroll
  for (int t = 0; t < KNB; ++t) h[t] = ~0ULL;
  for (int j = 0; j < NPTS; ++j) {
    float px = sx[j], py = sy[j], pz = sz[j];
    float inner = fmaf(pz, qz, fmaf(py, qy, px * qx));
    float jn = fmaf(pz, pz, fmaf(py, py, px * px));
    float pd = (2.0f * inner - qn) - jn;
    heap_insert(h, mkkey(pd, j));
  }
  int* op = idxo + ((size_t)(b * NPTS + i)) * KNB;
#pragma unroll
  for (int t = 0; t < KNB; ++t) op[t] = (int)(h[t] & 0xFFFFFFFFu);
}

// ---------------- row squared norms for 64-wide features ----------------
__global__ __launch_bounds__(256) void rownormk(const float* __restrict__ f, float* __restrict__ nrm) {
  int r = blockIdx.x * 256 + threadIdx.x;
  const float* p = f + (size_t)r * 64;
  float a0 = 0, a1 = 0, a2 = 0, a3 = 0;
#pragma unroll
  for (int c4 = 0; c4 < 16; ++c4) {
    float4 v = *(const float4*)(p + c4 * 4);
    a0 = fmaf(v.x, v.x, a0);
    a1 = fmaf(v.y, v.y, a1);
    a2 = fmaf(v.z, v.z, a2);
    a3 = fmaf(v.w, v.w, a3);
  }
  nrm[r] = (a0 + a1) + (a2 + a3);
}

// ---------------- kNN on 64-wide features (feat (B,N,64) row-major) ----------------
// block 256 = 4 waves; 16 queries/wave; 4 lanes per query (j interleaved mod 4)
__global__ __launch_bounds__(256) void knn_c64(const float* __restrict__ feat, const float* __restrict__ nrm,
                                               int* __restrict__ idxo) {
  __shared__ unsigned long long smem[5120];  // 40KB: tile (128x68 f32 + 128 f32) / merge (256*20 u64)
  float* fs = (float*)smem;
  float* snt = fs + 128 * 68;
  int b = blockIdx.y, tid = threadIdx.x;
  int wave = tid >> 6, lane = tid & 63;
  int qg = lane >> 2, tq = lane & 3;
  int i = blockIdx.x * 64 + wave * 16 + qg;
  const float* fb = feat + (size_t)b * NPTS * 64;
  const float* nb = nrm + b * NPTS;
  float q[64];
#pragma unroll
  for (int c4 = 0; c4 < 16; ++c4) {
    float4 v = *(const float4*)(fb + (size_t)i * 64 + c4 * 4);
    q[c4 * 4 + 0] = v.x;
    q[c4 * 4 + 1] = v.y;
    q[c4 * 4 + 2] = v.z;
    q[c4 * 4 + 3] = v.w;
  }
  float qn = nb[i];
  unsigned long long h[KNB];
#pragma unroll
  for (int t = 0; t < KNB; ++t) h[t] = ~0ULL;

  for (int j0 = 0; j0 < NPTS; j0 += 128) {
    __syncthreads();
#pragma unroll
    for (int l = 0; l < 8; ++l) {
      int v = tid + l * 256;
      int row = v >> 4, c4 = (v & 15) * 4;
      float4 t4 = *(const float4*)(fb + (size_t)(j0 + row) * 64 + c4);
      *(float4*)(fs + row * 68 + c4) = t4;
    }
    if (tid < 128) snt[tid] = nb[j0 + tid];
    __syncthreads();
    for (int tt = 0; tt < 32; ++tt) {
      int jj = tt * 4 + tq;
      const float* fr = fs + jj * 68;
      float a0 = 0, a1 = 0, a2 = 0, a3 = 0;
#pragma unroll
      for (int c4 = 0; c4 < 16; ++c4) {
        float4 v = *(const float4*)(fr + c4 * 4);
        a0 = fmaf(v.x, q[c4 * 4 + 0], a0);
        a1 = fmaf(v.y, q[c4 * 4 + 1], a1);
        a2 = fmaf(v.z, q[c4 * 4 + 2], a2);
        a3 = fmaf(v.w, q[c4 * 4 + 3], a3);
      }
      float dot = (a0 + a1) + (a2 + a3);
      float pd = (2.0f * dot - qn) - snt[jj];
      heap_insert(h, mkkey(pd, j0 + jj));
    }
  }
  __syncthreads();  // protect tile region before reuse as merge buffer
  unsigned long long* mb = smem;
#pragma unroll
  for (int t = 0; t < KNB; ++t) mb[(size_t)tid * KNB + t] = h[t];
  __syncthreads();
  if (tq == 0) {
    int p0 = 0, p1 = 0, p2 = 0, p3 = 0;
    const unsigned long long* l0 = mb + (size_t)(tid + 0) * KNB;
    const unsigned long long* l1 = mb + (size_t)(tid + 1) * KNB;
    const unsigned long long* l2 = mb + (size_t)(tid + 2) * KNB;
    const unsigned long long* l3 = mb + (size_t)(tid + 3) * KNB;
    int* op = idxo + ((size_t)(b * NPTS + i)) * KNB;
    for (int t = 0; t < KNB; ++t) {
      unsigned long long u0 = (p0 < KNB) ? l0[p0] : ~0ULL;
      unsigned long long u1 = (p1 < KNB) ? l1[p1] : ~0ULL;
      unsigned long long u2 = (p2 < KNB) ? l2[p2] : ~0ULL;
      unsigned long long u3 = (p3 < KNB) ? l3[p3] : ~0ULL;
      unsigned long long m01 = u0 < u1 ? u0 : u1;
      int s01 = u0 < u1 ? 0 : 1;
      unsigned long long m23 = u2 < u3 ? u2 : u3;
      int s23 = u2 < u3 ? 2 : 3;
      unsigned long long mm = m01 < m23 ? m01 : m23;
      int sm = m01 < m23 ? s01 : s23;
      p0 += (sm == 0);
      p1 += (sm == 1);
      p2 += (sm == 2);
      p3 += (sm == 3);
      op[t] = (int)(mm & 0xFFFFFFFFu);
    }
  }
}

// ---------------- fused edge conv: gather->conv1(->conv2)->max over 20 ----------------
// block handles 4 queries = 80 edge rows; GEMM tile 80 x 64
template <int CIN, bool CONV2, bool CHMAJOR>
__global__ __launch_bounds__(256) void edgeconv(const float* __restrict__ src, const int* __restrict__ idx,
                                                const float* __restrict__ w1, const float* __restrict__ s1,
                                                const float* __restrict__ b1, const float* __restrict__ w2,
                                                const float* __restrict__ s2, const float* __restrict__ b2,
                                                float* __restrict__ outp) {
  constexpr int KS = (CIN < 16) ? CIN : 16;
  constexpr int HALF = CIN / 2;
  __shared__ float As[16][84];
  __shared__ float Ws[16][68];
  __shared__ float C1s[80][68];
  __shared__ float W4s[64][68];
  __shared__ float part[16][68];

  int t = threadIdx.x;
  int tx = t & 15, ty = t >> 4;
  int q0 = blockIdx.x * 4;
  int b = q0 >> 12;
  int n0 = q0 & (NPTS - 1);
  const int* idxb = idx + (size_t)q0 * KNB;

  if (CONV2) {
    for (int e = t; e < 64 * 64; e += 256) {
      int o = e >> 6, c = e & 63;
      W4s[c][o] = w2[e];  // w2[o*64+c]
    }
  }

  float acc1[5][4];
#pragma unroll
  for (int r = 0; r < 5; ++r)
#pragma unroll
    for (int j = 0; j < 4; ++j) acc1[r][j] = 0.f;

  for (int k0 = 0; k0 < CIN; k0 += KS) {
    __syncthreads();
    if (CHMAJOR) {  // src is (B,3,N)
      const float* sb = src + (size_t)b * 3 * NPTS;
      for (int e = t; e < 80 * KS; e += 256) {
        int row = e / KS, kk = e % KS;
        int nq = row / KNB, k20 = row % KNB;
        int n = n0 + nq;
        int jn2 = idxb[nq * KNB + k20];
        float v;
        if (kk < 3)
          v = sb[kk * NPTS + jn2] - sb[kk * NPTS + n];
        else
          v = sb[(kk - 3) * NPTS + n];
        As[kk][row] = v;
      }
    } else {  // src is (B,N,64)
      const float* sb = src + (size_t)b * NPTS * 64;
      for (int v4 = t; v4 < 80 * 4; v4 += 256) {
        int row = v4 >> 2, kq = v4 & 3;
        int c = k0 + kq * 4;
        int nq = row / KNB, k20 = row % KNB;
        int n = n0 + nq;
        float4 val;
        if (c < HALF) {
          int jn2 = idxb[nq * KNB + k20];
          float4 nbv = *(const float4*)(sb + (size_t)jn2 * 64 + c);
          float4 ctv = *(const float4*)(sb + (size_t)n * 64 + c);
          val = make_float4(nbv.x - ctv.x, nbv.y - ctv.y, nbv.z - ctv.z, nbv.w - ctv.w);
        } else {
          val = *(const float4*)(sb + (size_t)n * 64 + (c - HALF));
        }
        As[kq * 4 + 0][row] = val.x;
        As[kq * 4 + 1][row] = val.y;
        As[kq * 4 + 2][row] = val.z;
        As[kq * 4 + 3][row] = val.w;
      }
    }
    for (int e = t; e < 64 * KS; e += 256) {
      int o = e / KS, kk = e % KS;
      Ws[kk][o] = w1[o * CIN + k0 + kk];
    }
    __syncthreads();
#pragma unroll
    for (int kk = 0; kk < KS; ++kk) {
      float av[5];
      av[0] = As[kk][ty * 5 + 0];
      av[1] = As[kk][ty * 5 + 1];
      av[2] = As[kk][ty * 5 + 2];
      av[3] = As[kk][ty * 5 + 3];
      av[4] = As[kk][ty * 5 + 4];
      float4 bb = *(const float4*)&Ws[kk][tx * 4];
#pragma unroll
      for (int r = 0; r < 5; ++r) {
        acc1[r][0] = fmaf(av[r], bb.x, acc1[r][0]);
        acc1[r][1] = fmaf(av[r], bb.y, acc1[r][1]);
        acc1[r][2] = fmaf(av[r], bb.z, acc1[r][2]);
        acc1[r][3] = fmaf(av[r], bb.w, acc1[r][3]);
      }
    }
  }
  __syncthreads();
  float4 sv = *(const float4*)(s1 + tx * 4);
  float4 bv = *(const float4*)(b1 + tx * 4);
  float pmax[4];
#pragma unroll
  for (int j = 0; j < 4; ++j) pmax[j] = -3.4e38f;

  if (CONV2) {
#pragma unroll
    for (int r = 0; r < 5; ++r) {
      C1s[ty * 5 + r][tx * 4 + 0] = leaky(fmaf(acc1[r][0], sv.x, bv.x));
      C1s[ty * 5 + r][tx * 4 + 1] = leaky(fmaf(acc1[r][1], sv.y, bv.y));
      C1s[ty * 5 + r][tx * 4 + 2] = leaky(fmaf(acc1[r][2], sv.z, bv.z));
      C1s[ty * 5 + r][tx * 4 + 3] = leaky(fmaf(acc1[r][3], sv.w, bv.w));
    }
    __syncthreads();
    float acc2[5][4];
#pragma unroll
    for (int r = 0; r < 5; ++r)
#pragma unroll
      for (int j = 0; j < 4; ++j) acc2[r][j] = 0.f;
#pragma unroll
    for (int c = 0; c < 64; ++c) {
      float4 wb = *(const float4*)&W4s[c][tx * 4];
      float a0 = C1s[ty * 5 + 0][c];
      float a1 = C1s[ty * 5 + 1][c];
      float a2 = C1s[ty * 5 + 2][c];
      float a3 = C1s[ty * 5 + 3][c];
      float a4 = C1s[ty * 5 + 4][c];
      acc2[0][0] = fmaf(a0, wb.x, acc2[0][0]);
      acc2[0][1] = fmaf(a0, wb.y, acc2[0][1]);
      acc2[0][2] = fmaf(a0, wb.z, acc2[0][2]);
      acc2[0][3] = fmaf(a0, wb.w, acc2[0][3]);
      acc2[1][0] = fmaf(a1, wb.x, acc2[1][0]);
      acc2[1][1] = fmaf(a1, wb.y, acc2[1][1]);
      acc2[1][2] = fmaf(a1, wb.z, acc2[1][2]);
      acc2[1][3] = fmaf(a1, wb.w, acc2[1][3]);
      acc2[2][0] = fmaf(a2, wb.x, acc2[2][0]);
      acc2[2][1] = fmaf(a2, wb.y, acc2[2][1]);
      acc2[2][2] = fmaf(a2, wb.z, acc2[2][2]);
      acc2[2][3] = fmaf(a2, wb.w, acc2[2][3]);
      acc2[3][0] = fmaf(a3, wb.x, acc2[3][0]);
      acc2[3][1] = fmaf(a3, wb.y, acc2[3][1]);
      acc2[3][2] = fmaf(a3, wb.z, acc2[3][2]);
      acc2[3][3] = fmaf(a3, wb.w, acc2[3][3]);
      acc2[4][0] = fmaf(a4, wb.x, acc2[4][0]);
      acc2[4][1] = fmaf(a4, wb.y, acc2[4][1]);
      acc2[4][2] = fmaf(a4, wb.z, acc2[4][2]);
      acc2[4][3] = fmaf(a4, wb.w, acc2[4][3]);
    }
    float4 s2v = *(const float4*)(s2 + tx * 4);
    float4 b2v = *(const float4*)(b2 + tx * 4);
#pragma unroll
    for (int r = 0; r < 5; ++r) {
      pmax[0] = fmaxf(pmax[0], leaky(fmaf(acc2[r][0], s2v.x, b2v.x)));
      pmax[1] = fmaxf(pmax[1], leaky(fmaf(acc2[r][1], s2v.y, b2v.y)));
      pmax[2] = fmaxf(pmax[2], leaky(fmaf(acc2[r][2], s2v.z, b2v.z)));
      pmax[3] = fmaxf(pmax[3], leaky(fmaf(acc2[r][3], s2v.w, b2v.w)));
    }
  } else {
#pragma unroll
    for (int r = 0; r < 5; ++r) {
      pmax[0] = fmaxf(pmax[0], leaky(fmaf(acc1[r][0], sv.x, bv.x)));
      pmax[1] = fmaxf(pmax[1], leaky(fmaf(acc1[r][1], sv.y, bv.y)));
      pmax[2] = fmaxf(pmax[2], leaky(fmaf(acc1[r][2], sv.z, bv.z)));
      pmax[3] = fmaxf(pmax[3], leaky(fmaf(acc1[r][3], sv.w, bv.w)));
    }
  }
  part[ty][tx * 4 + 0] = pmax[0];
  part[ty][tx * 4 + 1] = pmax[1];
  part[ty][tx * 4 + 2] = pmax[2];
  part[ty][tx * 4 + 3] = pmax[3];
  __syncthreads();
  {
    int q = t >> 6, o = t & 63;
    float m = part[q * 4 + 0][o];
    m = fmaxf(m, part[q * 4 + 1][o]);
    m = fmaxf(m, part[q * 4 + 2][o]);
    m = fmaxf(m, part[q * 4 + 3][o]);
    outp[((size_t)(q0 + q)) * 64 + o] = m;
  }
}

// ---------------- generic tiled SGEMM: C = epi(A @ W^T) ----------------
#define AM_CAT3 0
#define AM_ROW 1
#define EPI_STORE 0
#define EPI_ADDG 1
#define EPI_MAX 2

template <int AMODE, int EPI>
__global__ __launch_bounds__(256) void gemmk(const float* __restrict__ a0, const float* __restrict__ a1,
                                             const float* __restrict__ a2, const float* __restrict__ w, int ldw,
                                             int Ksz, const float* __restrict__ sc, const float* __restrict__ bi,
                                             const float* __restrict__ gadd, float* __restrict__ outp, int ldo,
                                             unsigned* __restrict__ gmax) {
  __shared__ float As[16][68];
  __shared__ float Bs[16][68];
  int t = threadIdx.x, tx = t & 15, ty = t >> 4;
  int row0 = blockIdx.x * 64;
  int o0 = blockIdx.y * 64;
  float acc[4][4];
#pragma unroll
  for (int i = 0; i < 4; ++i)
#pragma unroll
    for (int j = 0; j < 4; ++j) acc[i][j] = 0.f;
  int arow = t >> 2;
  int ak4 = (t & 3) * 4;
  for (int k0 = 0; k0 < Ksz; k0 += 16) {
    __syncthreads();
    {
      int r = row0 + arow;
      int c = k0 + ak4;
      float4 v;
      if (AMODE == AM_CAT3) {
        const float* s = (c < 64) ? a0 : (c < 128 ? a1 : a2);
        v = *(const float4*)(s + (size_t)r * 64 + (c & 63));
      } else {
        v = *(const float4*)(a0 + (size_t)r * Ksz + c);
      }
      As[ak4 + 0][arow] = v.x;
      As[ak4 + 1][arow] = v.y;
      As[ak4 + 2][arow] = v.z;
      As[ak4 + 3][arow] = v.w;
      float4 wv = *(const float4*)(w + (size_t)(o0 + arow) * ldw + c);
      Bs[ak4 + 0][arow] = wv.x;
      Bs[ak4 + 1][arow] = wv.y;
      Bs[ak4 + 2][arow] = wv.z;
      Bs[ak4 + 3][arow] = wv.w;
    }
    __syncthreads();
#pragma unroll
    for (int kk = 0; kk < 16; ++kk) {
      float4 a = *(const float4*)&As[kk][ty * 4];
      float4 bb = *(const float4*)&Bs[kk][tx * 4];
      acc[0][0] = fmaf(a.x, bb.x, acc[0][0]);
      acc[0][1] = fmaf(a.x, bb.y, acc[0][1]);
      acc[0][2] = fmaf(a.x, bb.z, acc[0][2]);
      acc[0][3] = fmaf(a.x, bb.w, acc[0][3]);
      acc[1][0] = fmaf(a.y, bb.x, acc[1][0]);
      acc[1][1] = fmaf(a.y, bb.y, acc[1][1]);
      acc[1][2] = fmaf(a.y, bb.z, acc[1][2]);
      acc[1][3] = fmaf(a.y, bb.w, acc[1][3]);
      acc[2][0] = fmaf(a.z, bb.x, acc[2][0]);
      acc[2][1] = fmaf(a.z, bb.y, acc[2][1]);
      acc[2][2] = fmaf(a.z, bb.z, acc[2][2]);
      acc[2][3] = fmaf(a.z, bb.w, acc[2][3]);
      acc[3][0] = fmaf(a.w, bb.x, acc[3][0]);
      acc[3][1] = fmaf(a.w, bb.y, acc[3][1]);
      acc[3][2] = fmaf(a.w, bb.z, acc[3][2]);
      acc[3][3] = fmaf(a.w, bb.w, acc[3][3]);
    }
  }
  float4 sv = *(const float4*)(sc + o0 + tx * 4);
  float4 bv = *(const float4*)(bi + o0 + tx * 4);
  if (EPI == EPI_MAX) {
    __syncthreads();
    float pm[4] = {-3.4e38f, -3.4e38f, -3.4e38f, -3.4e38f};
#pragma unroll
    for (int i = 0; i < 4; ++i) {
      pm[0] = fmaxf(pm[0], leaky(fmaf(acc[i][0], sv.x, bv.x)));
      pm[1] = fmaxf(pm[1], leaky(fmaf(acc[i][1], sv.y, bv.y)));
      pm[2] = fmaxf(pm[2], leaky(fmaf(acc[i][2], sv.z, bv.z)));
      pm[3] = fmaxf(pm[3], leaky(fmaf(acc[i][3], sv.w, bv.w)));
    }
    As[ty][tx * 4 + 0] = pm[0];
    As[ty][tx * 4 + 1] = pm[1];
    As[ty][tx * 4 + 2] = pm[2];
    As[ty][tx * 4 + 3] = pm[3];
    __syncthreads();
    if (t < 64) {
      float m = As[0][t];
#pragma unroll
      for (int g = 1; g < 16; ++g) m = fmaxf(m, As[g][t]);
      int b = row0 >> 12;
      atomicMax(&gmax[b * 1024 + o0 + t], encf(m));
    }
  } else {
    float4 ga = make_float4(0.f, 0.f, 0.f, 0.f);
    if (EPI == EPI_ADDG) ga = *(const float4*)(gadd + (row0 >> 12) * 256 + o0 + tx * 4);
#pragma unroll
    for (int i = 0; i < 4; ++i) {
      int r = row0 + ty * 4 + i;
      float4 ov;
      ov.x = leaky(fmaf(acc[i][0] + ga.x, sv.x, bv.x));
      ov.y = leaky(fmaf(acc[i][1] + ga.y, sv.y, bv.y));
      ov.z = leaky(fmaf(acc[i][2] + ga.z, sv.z, bv.z));
      ov.w = leaky(fmaf(acc[i][3] + ga.w, sv.w, bv.w));
      *(float4*)(outp + (size_t)r * ldo + o0 + tx * 4) = ov;
    }
  }
}

// ---------------- per-batch g . w8[:, :1024] ----------------
__global__ __launch_bounds__(256) void gdotk(const unsigned* __restrict__ gmax, const float* __restrict__ w8,
                                             float* __restrict__ gb8) {
  int wv = blockIdx.x * 4 + (threadIdx.x >> 6);
  int lane = threadIdx.x & 63;
  int b = wv >> 8, o = wv & 255;
  const float* wr = w8 + (size_t)o * 1216;
  const unsigned* gr = gmax + b * 1024;
  float acc = 0.f;
#pragma unroll
  for (int l = 0; l < 4; ++l) {
    int c = lane * 4 + l * 256;
    float4 wv4 = *(const float4*)(wr + c);
    acc = fmaf(decf(gr[c + 0]), wv4.x, acc);
    acc = fmaf(decf(gr[c + 1]), wv4.y, acc);
    acc = fmaf(decf(gr[c + 2]), wv4.z, acc);
    acc = fmaf(decf(gr[c + 3]), wv4.w, acc);
  }
#pragma unroll
  for (int off = 32; off >= 1; off >>= 1) acc += __shfl_down(acc, off);
  if (lane == 0) gb8[b * 256 + o] = acc;
}

// ---------------- final 128 -> 13 projection + transpose ----------------
__global__ __launch_bounds__(256) void outk(const float* __restrict__ h10, const float* __restrict__ w11,
                                            float* __restrict__ outp) {
  __shared__ float hs[64][132];
  __shared__ float wsm[13][128];
  int b = blockIdx.y, n0 = blockIdx.x * 64, t = threadIdx.x;
  for (int e = t; e < 13 * 128; e += 256) wsm[e >> 7][e & 127] = w11[e];
  const float* hb = h10 + ((size_t)(b * NPTS + n0)) * 128;
#pragma unroll
  for (int l = 0; l < 8; ++l) {
    int v = t + l * 256;
    int row = v >> 5, c4 = (v & 31) * 4;
    *(float4*)(&hs[row][c4]) = *(const float4*)(hb + (size_t)row * 128 + c4);
  }
  __syncthreads();
  for (int e = t; e < 13 * 64; e += 256) {
    int o = e >> 6, n = e & 63;
    float a0 = 0, a1 = 0, a2 = 0, a3 = 0;
#pragma unroll
    for (int c4 = 0; c4 < 32; ++c4) {
      float4 hv = *(const float4*)(&hs[n][c4 * 4]);
      const float* wr = &wsm[o][c4 * 4];
      a0 = fmaf(hv.x, wr[0], a0);
      a1 = fmaf(hv.y, wr[1], a1);
      a2 = fmaf(hv.z, wr[2], a2);
      a3 = fmaf(hv.w, wr[3], a3);
    }
    outp[((size_t)b * 13 + o) * NPTS + n0 + n] = (a0 + a1) + (a2 + a3);
  }
}

extern "C" void kernel_launch(void* const* d_in, const int* in_sizes, int n_in, void* d_out, int out_size, void* d_ws,
                              size_t ws_size, hipStream_t stream) {
  (void)in_sizes;
  (void)n_in;
  (void)out_size;
  (void)ws_size;
  const float* x = (const float*)d_in[0];
  const float* w1 = (const float*)d_in[1];
  const float* s1 = (const float*)d_in[2];
  const float* b1 = (const float*)d_in[3];
  const float* w2 = (const float*)d_in[4];
  const float* s2 = (const float*)d_in[5];
  const float* b2 = (const float*)d_in[6];
  const float* w3 = (const float*)d_in[7];
  const float* s3 = (const float*)d_in[8];
  const float* b3 = (const float*)d_in[9];
  const float* w4 = (const float*)d_in[10];
  const float* s4 = (const float*)d_in[11];
  const float* b4 = (const float*)d_in[12];
  const float* w5 = (const float*)d_in[13];
  const float* s5 = (const float*)d_in[14];
  const float* b5 = (const float*)d_in[15];
  const float* w6 = (const float*)d_in[16];
  const float* s6 = (const float*)d_in[17];
  const float* b6 = (const float*)d_in[18];
  const float* w8 = (const float*)d_in[19];
  const float* s8 = (const float*)d_in[20];
  const float* b8 = (const float*)d_in[21];
  const float* w9 = (const float*)d_in[22];
  const float* s9 = (const float*)d_in[23];
  const float* b9 = (const float*)d_in[24];
  const float* w10 = (const float*)d_in[25];
  const float* s10 = (const float*)d_in[26];
  const float* b10 = (const float*)d_in[27];
  const float* w11 = (const float*)d_in[28];

  float* ws = (float*)d_ws;
  size_t off = 0;
  int* idxb = (int*)ws;
  off += 655360;  // B*N*20
  float* x1 = ws + off;
  off += 2097152;
  float* x2 = ws + off;
  off += 2097152;
  float* x3 = ws + off;
  off += 2097152;
  float* nrm = ws + off;
  off += 131072;
  unsigned* gmax = (unsigned*)(ws + off);
  off += 8192;
  float* gb8 = ws + off;
  off += 2048;
  float* h8 = ws + off;
  off += 8388608;
  float* h9 = ws + off;
  off += 8388608;
  float* h10 = h8;  // reuse (h8 dead after l9)
  float* outp = (float*)d_out;

  knn_c3<<<dim3(16, BATCH), 256, 0, stream>>>(x, idxb);
  edgeconv<6, true, true><<<dim3(8192), 256, 0, stream>>>(x, idxb, w1, s1, b1, w2, s2, b2, x1);
  rownormk<<<dim3(128), 256, 0, stream>>>(x1, nrm);
  knn_c64<<<dim3(64, BATCH), 256, 0, stream>>>(x1, nrm, idxb);
  edgeconv<128, true, false><<<dim3(8192), 256, 0, stream>>>(x1, idxb, w3, s3, b3, w4, s4, b4, x2);
  rownormk<<<dim3(128), 256, 0, stream>>>(x2, nrm);
  knn_c64<<<dim3(64, BATCH), 256, 0, stream>>>(x2, nrm, idxb);
  edgeconv<128, false, false><<<dim3(8192), 256, 0, stream>>>(x2, idxb, w5, s5, b5, nullptr, nullptr, nullptr, x3);
  hipMemsetAsync(gmax, 0, 8192 * sizeof(unsigned), stream);
  gemmk<AM_CAT3, EPI_MAX><<<dim3(512, 16), 256, 0, stream>>>(x1, x2, x3, w6, 192, 192, s6, b6, nullptr, nullptr, 0,
                                                             gmax);
  gdotk<<<dim3(512), 256, 0, stream>>>(gmax, w8, gb8);
  gemmk<AM_CAT3, EPI_ADDG><<<dim3(512, 4), 256, 0, stream>>>(x1, x2, x3, w8 + 1024, 1216, 192, s8, b8, gb8, h8, 256,
                                                             nullptr);
  gemmk<AM_ROW, EPI_STORE><<<dim3(512, 4), 256, 0, stream>>>(h8, nullptr, nullptr, w9, 256, 256, s9, b9, nullptr, h9,
                                                             256, nullptr);
  gemmk<AM_ROW, EPI_STORE><<<dim3(512, 2), 256, 0, stream>>>(h9, nullptr, nullptr, w10, 256, 256, s10, b10, nullptr,
                                                             h10, 128, nullptr);
  outk<<<dim3(64, BATCH), 256, 0, stream>>>(h10, w11, outp);
}

// Round 2
// 3160.993 us; speedup vs baseline: 1.4844x; 1.4844x over previous
//
#include <hip/hip_runtime.h>
#include <cstdint>
#include <cstddef>

#define NPTS 4096
#define BATCH 8
#define KNB 20

__device__ __forceinline__ float leaky(float v) { return v > 0.f ? v : 0.2f * v; }

__device__ __forceinline__ unsigned encf(float f) {
  unsigned u = __float_as_uint(f);
  return (u & 0x80000000u) ? ~u : (u | 0x80000000u);
}
__device__ __forceinline__ float decf(unsigned e) {
  unsigned u = (e & 0x80000000u) ? (e & 0x7FFFFFFFu) : ~e;
  return __uint_as_float(u);
}

// key = (~sortable(pd)) << 32 | j : smallest key = largest pd, ties -> smallest j
__device__ __forceinline__ unsigned long long mkkey(float pd, int j) {
  unsigned s = encf(pd);
  return (((unsigned long long)(~s)) << 32) | (unsigned)j;
}

// ---- top-20 insert, split float/int sorted list (descending pd) ----
// strict > keeps earlier-scanned (smaller j within a lane) on ties
__device__ __forceinline__ void tk_insert(float (&hf)[KNB], int (&hj)[KNB], float pd, int j) {
  if (pd > hf[KNB - 1]) {
    float cf = pd;
    int cj = j;
#pragma unroll
    for (int t = 0; t < KNB; ++t) {
      bool gt = cf > hf[t];
      float nf = gt ? cf : hf[t];
      int nj = gt ? cj : hj[t];
      cf = gt ? hf[t] : cf;
      cj = gt ? hj[t] : cj;
      hf[t] = nf;
      hj[t] = nj;
    }
  }
}

#define NEGINF (__int_as_float(0xff800000))

// ---------------- kNN on 3-d input points (x is (B,3,N)) ----------------
// 4 lanes/query, 64 queries/block, j tiled 1024 in LDS as float4(x,y,z,norm)
__global__ __launch_bounds__(256) void knn_c3(const float* __restrict__ x, int* __restrict__ idxo) {
  __shared__ unsigned long long smem[5120];  // 40KB: tile phase 16KB / merge 40KB
  float4* sp = (float4*)smem;
  int b = blockIdx.y, tid = threadIdx.x;
  int wave = tid >> 6, lane = tid & 63;
  int qg = lane >> 2, tq = lane & 3;
  int i = blockIdx.x * 64 + wave * 16 + qg;
  const float* xb = x + (size_t)b * 3 * NPTS;
  float qx = xb[i], qy = xb[NPTS + i], qz = xb[2 * NPTS + i];
  float qn = fmaf(qz, qz, fmaf(qy, qy, qx * qx));
  float hf[KNB];
  int hj[KNB];
#pragma unroll
  for (int t = 0; t < KNB; ++t) {
    hf[t] = NEGINF;
    hj[t] = 0x7fffffff;
  }
  for (int j0 = 0; j0 < NPTS; j0 += 1024) {
    __syncthreads();
#pragma unroll
    for (int l = 0; l < 4; ++l) {
      int p = tid + l * 256;
      float px = xb[j0 + p], py = xb[NPTS + j0 + p], pz = xb[2 * NPTS + j0 + p];
      float pn = fmaf(pz, pz, fmaf(py, py, px * px));
      sp[p] = make_float4(px, py, pz, pn);
    }
    __syncthreads();
#pragma unroll 4
    for (int tt = 0; tt < 256; ++tt) {
      int jj = tt * 4 + tq;
      float4 p = sp[jj];
      float inner = fmaf(p.x, qx, fmaf(p.y, qy, p.z * qz));
      float pd = fmaf(2.0f, inner, -qn) - p.w;
      tk_insert(hf, hj, pd, j0 + jj);
    }
  }
  __syncthreads();
  unsigned long long* mb = smem;
#pragma unroll
  for (int t = 0; t < KNB; ++t) mb[(size_t)tid * KNB + t] = mkkey(hf[t], hj[t]);
  __syncthreads();
  if (tq == 0) {
    int p0 = 0, p1 = 0, p2 = 0, p3 = 0;
    const unsigned long long* l0 = mb + (size_t)(tid + 0) * KNB;
    const unsigned long long* l1 = mb + (size_t)(tid + 1) * KNB;
    const unsigned long long* l2 = mb + (size_t)(tid + 2) * KNB;
    const unsigned long long* l3 = mb + (size_t)(tid + 3) * KNB;
    int* op = idxo + ((size_t)(b * NPTS + i)) * KNB;
    for (int t = 0; t < KNB; ++t) {
      unsigned long long u0 = (p0 < KNB) ? l0[p0] : ~0ULL;
      unsigned long long u1 = (p1 < KNB) ? l1[p1] : ~0ULL;
      unsigned long long u2 = (p2 < KNB) ? l2[p2] : ~0ULL;
      unsigned long long u3 = (p3 < KNB) ? l3[p3] : ~0ULL;
      unsigned long long m01 = u0 < u1 ? u0 : u1;
      int s01 = u0 < u1 ? 0 : 1;
      unsigned long long m23 = u2 < u3 ? u2 : u3;
      int s23 = u2 < u3 ? 2 : 3;
      unsigned long long mm = m01 < m23 ? m01 : m23;
      int sm = m01 < m23 ? s01 : s23;
      p0 += (sm == 0);
      p1 += (sm == 1);
      p2 += (sm == 2);
      p3 += (sm == 3);
      op[t] = (int)(mm & 0xFFFFFFFFu);
    }
  }
}

// ---------------- row squared norms for 64-wide features ----------------
__global__ __launch_bounds__(256) void rownormk(const float* __restrict__ f, float* __restrict__ nrm) {
  int r = blockIdx.x * 256 + threadIdx.x;
  const float* p = f + (size_t)r * 64;
  float a0 = 0, a1 = 0, a2 = 0, a3 = 0;
#pragma unroll
  for (int c4 = 0; c4 < 16; ++c4) {
    float4 v = *(const float4*)(p + c4 * 4);
    a0 = fmaf(v.x, v.x, a0);
    a1 = fmaf(v.y, v.y, a1);
    a2 = fmaf(v.z, v.z, a2);
    a3 = fmaf(v.w, v.w, a3);
  }
  nrm[r] = (a0 + a1) + (a2 + a3);
}

// ---------------- kNN on 64-wide features (feat (B,N,64) row-major) ----------------
// block 256 = 4 waves; 16 queries/wave; 4 lanes per query (j interleaved mod 4)
__global__ __launch_bounds__(256) void knn_c64(const float* __restrict__ feat, const float* __restrict__ nrm,
                                               int* __restrict__ idxo) {
  __shared__ unsigned long long smem[5120];  // 40KB: tile (128x68 f32 + 128 f32) / merge (256*20 u64)
  float* fs = (float*)smem;
  float* snt = fs + 128 * 68;
  int b = blockIdx.y, tid = threadIdx.x;
  int wave = tid >> 6, lane = tid & 63;
  int qg = lane >> 2, tq = lane & 3;
  int i = blockIdx.x * 64 + wave * 16 + qg;
  const float* fb = feat + (size_t)b * NPTS * 64;
  const float* nb = nrm + b * NPTS;
  float q[64];
#pragma unroll
  for (int c4 = 0; c4 < 16; ++c4) {
    float4 v = *(const float4*)(fb + (size_t)i * 64 + c4 * 4);
    q[c4 * 4 + 0] = v.x;
    q[c4 * 4 + 1] = v.y;
    q[c4 * 4 + 2] = v.z;
    q[c4 * 4 + 3] = v.w;
  }
  float qn = nb[i];
  float hf[KNB];
  int hj[KNB];
#pragma unroll
  for (int t = 0; t < KNB; ++t) {
    hf[t] = NEGINF;
    hj[t] = 0x7fffffff;
  }

  for (int j0 = 0; j0 < NPTS; j0 += 128) {
    __syncthreads();
#pragma unroll
    for (int l = 0; l < 8; ++l) {
      int v = tid + l * 256;
      int row = v >> 4, c4 = (v & 15) * 4;
      float4 t4 = *(const float4*)(fb + (size_t)(j0 + row) * 64 + c4);
      *(float4*)(fs + row * 68 + c4) = t4;
    }
    if (tid < 128) snt[tid] = nb[j0 + tid];
    __syncthreads();
    for (int tt = 0; tt < 32; ++tt) {
      int jj = tt * 4 + tq;
      const float* fr = fs + jj * 68;
      float a0 = 0, a1 = 0, a2 = 0, a3 = 0;
#pragma unroll
      for (int c4 = 0; c4 < 16; ++c4) {
        float4 v = *(const float4*)(fr + c4 * 4);
        a0 = fmaf(v.x, q[c4 * 4 + 0], a0);
        a1 = fmaf(v.y, q[c4 * 4 + 1], a1);
        a2 = fmaf(v.z, q[c4 * 4 + 2], a2);
        a3 = fmaf(v.w, q[c4 * 4 + 3], a3);
      }
      float dot = (a0 + a1) + (a2 + a3);
      float pd = (2.0f * dot - qn) - snt[jj];
      tk_insert(hf, hj, pd, j0 + jj);
    }
  }
  __syncthreads();  // protect tile region before reuse as merge buffer
  unsigned long long* mb = smem;
#pragma unroll
  for (int t = 0; t < KNB; ++t) mb[(size_t)tid * KNB + t] = mkkey(hf[t], hj[t]);
  __syncthreads();
  if (tq == 0) {
    int p0 = 0, p1 = 0, p2 = 0, p3 = 0;
    const unsigned long long* l0 = mb + (size_t)(tid + 0) * KNB;
    const unsigned long long* l1 = mb + (size_t)(tid + 1) * KNB;
    const unsigned long long* l2 = mb + (size_t)(tid + 2) * KNB;
    const unsigned long long* l3 = mb + (size_t)(tid + 3) * KNB;
    int* op = idxo + ((size_t)(b * NPTS + i)) * KNB;
    for (int t = 0; t < KNB; ++t) {
      unsigned long long u0 = (p0 < KNB) ? l0[p0] : ~0ULL;
      unsigned long long u1 = (p1 < KNB) ? l1[p1] : ~0ULL;
      unsigned long long u2 = (p2 < KNB) ? l2[p2] : ~0ULL;
      unsigned long long u3 = (p3 < KNB) ? l3[p3] : ~0ULL;
      unsigned long long m01 = u0 < u1 ? u0 : u1;
      int s01 = u0 < u1 ? 0 : 1;
      unsigned long long m23 = u2 < u3 ? u2 : u3;
      int s23 = u2 < u3 ? 2 : 3;
      unsigned long long mm = m01 < m23 ? m01 : m23;
      int sm = m01 < m23 ? s01 : s23;
      p0 += (sm == 0);
      p1 += (sm == 1);
      p2 += (sm == 2);
      p3 += (sm == 3);
      op[t] = (int)(mm & 0xFFFFFFFFu);
    }
  }
}

// ---------------- fused edge conv: gather->conv1(->conv2)->max over 20 ----------------
// block handles 4 queries = 80 edge rows; GEMM tile 80 x 64
template <int CIN, bool CONV2, bool CHMAJOR>
__global__ __launch_bounds__(256) void edgeconv(const float* __restrict__ src, const int* __restrict__ idx,
                                                const float* __restrict__ w1, const float* __restrict__ s1,
                                                const float* __restrict__ b1, const float* __restrict__ w2,
                                                const float* __restrict__ s2, const float* __restrict__ b2,
                                                float* __restrict__ outp) {
  constexpr int KS = (CIN < 16) ? CIN : 16;
  constexpr int HALF = CIN / 2;
  __shared__ float As[16][84];
  __shared__ float Ws[16][68];
  __shared__ float C1s[80][68];
  __shared__ float W4s[64][68];
  __shared__ float part[16][68];

  int t = threadIdx.x;
  int tx = t & 15, ty = t >> 4;
  int q0 = blockIdx.x * 4;
  int b = q0 >> 12;
  int n0 = q0 & (NPTS - 1);
  const int* idxb = idx + (size_t)q0 * KNB;

  if (CONV2) {
    for (int e = t; e < 64 * 64; e += 256) {
      int o = e >> 6, c = e & 63;
      W4s[c][o] = w2[e];  // w2[o*64+c]
    }
  }

  float acc1[5][4];
#pragma unroll
  for (int r = 0; r < 5; ++r)
#pragma unroll
    for (int j = 0; j < 4; ++j) acc1[r][j] = 0.f;

  for (int k0 = 0; k0 < CIN; k0 += KS) {
    __syncthreads();
    if (CHMAJOR) {  // src is (B,3,N)
      const float* sb = src + (size_t)b * 3 * NPTS;
      for (int e = t; e < 80 * KS; e += 256) {
        int row = e / KS, kk = e % KS;
        int nq = row / KNB, k20 = row % KNB;
        int n = n0 + nq;
        int jn2 = idxb[nq * KNB + k20];
        float v;
        if (kk < 3)
          v = sb[kk * NPTS + jn2] - sb[kk * NPTS + n];
        else
          v = sb[(kk - 3) * NPTS + n];
        As[kk][row] = v;
      }
    } else {  // src is (B,N,64)
      const float* sb = src + (size_t)b * NPTS * 64;
      for (int v4 = t; v4 < 80 * 4; v4 += 256) {
        int row = v4 >> 2, kq = v4 & 3;
        int c = k0 + kq * 4;
        int nq = row / KNB, k20 = row % KNB;
        int n = n0 + nq;
        float4 val;
        if (c < HALF) {
          int jn2 = idxb[nq * KNB + k20];
          float4 nbv = *(const float4*)(sb + (size_t)jn2 * 64 + c);
          float4 ctv = *(const float4*)(sb + (size_t)n * 64 + c);
          val = make_float4(nbv.x - ctv.x, nbv.y - ctv.y, nbv.z - ctv.z, nbv.w - ctv.w);
        } else {
          val = *(const float4*)(sb + (size_t)n * 64 + (c - HALF));
        }
        As[kq * 4 + 0][row] = val.x;
        As[kq * 4 + 1][row] = val.y;
        As[kq * 4 + 2][row] = val.z;
        As[kq * 4 + 3][row] = val.w;
      }
    }
    for (int e = t; e < 64 * KS; e += 256) {
      int o = e / KS, kk = e % KS;
      Ws[kk][o] = w1[o * CIN + k0 + kk];
    }
    __syncthreads();
#pragma unroll
    for (int kk = 0; kk < KS; ++kk) {
      float av[5];
      av[0] = As[kk][ty * 5 + 0];
      av[1] = As[kk][ty * 5 + 1];
      av[2] = As[kk][ty * 5 + 2];
      av[3] = As[kk][ty * 5 + 3];
      av[4] = As[kk][ty * 5 + 4];
      float4 bb = *(const float4*)&Ws[kk][tx * 4];
#pragma unroll
      for (int r = 0; r < 5; ++r) {
        acc1[r][0] = fmaf(av[r], bb.x, acc1[r][0]);
        acc1[r][1] = fmaf(av[r], bb.y, acc1[r][1]);
        acc1[r][2] = fmaf(av[r], bb.z, acc1[r][2]);
        acc1[r][3] = fmaf(av[r], bb.w, acc1[r][3]);
      }
    }
  }
  __syncthreads();
  float4 sv = *(const float4*)(s1 + tx * 4);
  float4 bv = *(const float4*)(b1 + tx * 4);
  float pmax[4];
#pragma unroll
  for (int j = 0; j < 4; ++j) pmax[j] = -3.4e38f;

  if (CONV2) {
#pragma unroll
    for (int r = 0; r < 5; ++r) {
      C1s[ty * 5 + r][tx * 4 + 0] = leaky(fmaf(acc1[r][0], sv.x, bv.x));
      C1s[ty * 5 + r][tx * 4 + 1] = leaky(fmaf(acc1[r][1], sv.y, bv.y));
      C1s[ty * 5 + r][tx * 4 + 2] = leaky(fmaf(acc1[r][2], sv.z, bv.z));
      C1s[ty * 5 + r][tx * 4 + 3] = leaky(fmaf(acc1[r][3], sv.w, bv.w));
    }
    __syncthreads();
    float acc2[5][4];
#pragma unroll
    for (int r = 0; r < 5; ++r)
#pragma unroll
      for (int j = 0; j < 4; ++j) acc2[r][j] = 0.f;
#pragma unroll
    for (int c = 0; c < 64; ++c) {
      float4 wb = *(const float4*)&W4s[c][tx * 4];
      float a0 = C1s[ty * 5 + 0][c];
      float a1 = C1s[ty * 5 + 1][c];
      float a2 = C1s[ty * 5 + 2][c];
      float a3 = C1s[ty * 5 + 3][c];
      float a4 = C1s[ty * 5 + 4][c];
      acc2[0][0] = fmaf(a0, wb.x, acc2[0][0]);
      acc2[0][1] = fmaf(a0, wb.y, acc2[0][1]);
      acc2[0][2] = fmaf(a0, wb.z, acc2[0][2]);
      acc2[0][3] = fmaf(a0, wb.w, acc2[0][3]);
      acc2[1][0] = fmaf(a1, wb.x, acc2[1][0]);
      acc2[1][1] = fmaf(a1, wb.y, acc2[1][1]);
      acc2[1][2] = fmaf(a1, wb.z, acc2[1][2]);
      acc2[1][3] = fmaf(a1, wb.w, acc2[1][3]);
      acc2[2][0] = fmaf(a2, wb.x, acc2[2][0]);
      acc2[2][1] = fmaf(a2, wb.y, acc2[2][1]);
      acc2[2][2] = fmaf(a2, wb.z, acc2[2][2]);
      acc2[2][3] = fmaf(a2, wb.w, acc2[2][3]);
      acc2[3][0] = fmaf(a3, wb.x, acc2[3][0]);
      acc2[3][1] = fmaf(a3, wb.y, acc2[3][1]);
      acc2[3][2] = fmaf(a3, wb.z, acc2[3][2]);
      acc2[3][3] = fmaf(a3, wb.w, acc2[3][3]);
      acc2[4][0] = fmaf(a4, wb.x, acc2[4][0]);
      acc2[4][1] = fmaf(a4, wb.y, acc2[4][1]);
      acc2[4][2] = fmaf(a4, wb.z, acc2[4][2]);
      acc2[4][3] = fmaf(a4, wb.w, acc2[4][3]);
    }
    float4 s2v = *(const float4*)(s2 + tx * 4);
    float4 b2v = *(const float4*)(b2 + tx * 4);
#pragma unroll
    for (int r = 0; r < 5; ++r) {
      pmax[0] = fmaxf(pmax[0], leaky(fmaf(acc2[r][0], s2v.x, b2v.x)));
      pmax[1] = fmaxf(pmax[1], leaky(fmaf(acc2[r][1], s2v.y, b2v.y)));
      pmax[2] = fmaxf(pmax[2], leaky(fmaf(acc2[r][2], s2v.z, b2v.z)));
      pmax[3] = fmaxf(pmax[3], leaky(fmaf(acc2[r][3], s2v.w, b2v.w)));
    }
  } else {
#pragma unroll
    for (int r = 0; r < 5; ++r) {
      pmax[0] = fmaxf(pmax[0], leaky(fmaf(acc1[r][0], sv.x, bv.x)));
      pmax[1] = fmaxf(pmax[1], leaky(fmaf(acc1[r][1], sv.y, bv.y)));
      pmax[2] = fmaxf(pmax[2], leaky(fmaf(acc1[r][2], sv.z, bv.z)));
      pmax[3] = fmaxf(pmax[3], leaky(fmaf(acc1[r][3], sv.w, bv.w)));
    }
  }
  part[ty][tx * 4 + 0] = pmax[0];
  part[ty][tx * 4 + 1] = pmax[1];
  part[ty][tx * 4 + 2] = pmax[2];
  part[ty][tx * 4 + 3] = pmax[3];
  __syncthreads();
  {
    int q = t >> 6, o = t & 63;
    float m = part[q * 4 + 0][o];
    m = fmaxf(m, part[q * 4 + 1][o]);
    m = fmaxf(m, part[q * 4 + 2][o]);
    m = fmaxf(m, part[q * 4 + 3][o]);
    outp[((size_t)(q0 + q)) * 64 + o] = m;
  }
}

// ---------------- generic tiled SGEMM: C = epi(A @ W^T) ----------------
#define AM_CAT3 0
#define AM_ROW 1
#define EPI_STORE 0
#define EPI_ADDG 1
#define EPI_MAX 2

template <int AMODE, int EPI>
__global__ __launch_bounds__(256) void gemmk(const float* __restrict__ a0, const float* __restrict__ a1,
                                             const float* __restrict__ a2, const float* __restrict__ w, int ldw,
                                             int Ksz, const float* __restrict__ sc, const float* __restrict__ bi,
                                             const float* __restrict__ gadd, float* __restrict__ outp, int ldo,
                                             unsigned* __restrict__ gmax) {
  __shared__ float As[16][68];
  __shared__ float Bs[16][68];
  int t = threadIdx.x, tx = t & 15, ty = t >> 4;
  int row0 = blockIdx.x * 64;
  int o0 = blockIdx.y * 64;
  float acc[4][4];
#pragma unroll
  for (int i = 0; i < 4; ++i)
#pragma unroll
    for (int j = 0; j < 4; ++j) acc[i][j] = 0.f;
  int arow = t >> 2;
  int ak4 = (t & 3) * 4;
  for (int k0 = 0; k0 < Ksz; k0 += 16) {
    __syncthreads();
    {
      int r = row0 + arow;
      int c = k0 + ak4;
      float4 v;
      if (AMODE == AM_CAT3) {
        const float* s = (c < 64) ? a0 : (c < 128 ? a1 : a2);
        v = *(const float4*)(s + (size_t)r * 64 + (c & 63));
      } else {
        v = *(const float4*)(a0 + (size_t)r * Ksz + c);
      }
      As[ak4 + 0][arow] = v.x;
      As[ak4 + 1][arow] = v.y;
      As[ak4 + 2][arow] = v.z;
      As[ak4 + 3][arow] = v.w;
      float4 wv = *(const float4*)(w + (size_t)(o0 + arow) * ldw + c);
      Bs[ak4 + 0][arow] = wv.x;
      Bs[ak4 + 1][arow] = wv.y;
      Bs[ak4 + 2][arow] = wv.z;
      Bs[ak4 + 3][arow] = wv.w;
    }
    __syncthreads();
#pragma unroll
    for (int kk = 0; kk < 16; ++kk) {
      float4 a = *(const float4*)&As[kk][ty * 4];
      float4 bb = *(const float4*)&Bs[kk][tx * 4];
      acc[0][0] = fmaf(a.x, bb.x, acc[0][0]);
      acc[0][1] = fmaf(a.x, bb.y, acc[0][1]);
      acc[0][2] = fmaf(a.x, bb.z, acc[0][2]);
      acc[0][3] = fmaf(a.x, bb.w, acc[0][3]);
      acc[1][0] = fmaf(a.y, bb.x, acc[1][0]);
      acc[1][1] = fmaf(a.y, bb.y, acc[1][1]);
      acc[1][2] = fmaf(a.y, bb.z, acc[1][2]);
      acc[1][3] = fmaf(a.y, bb.w, acc[1][3]);
      acc[2][0] = fmaf(a.z, bb.x, acc[2][0]);
      acc[2][1] = fmaf(a.z, bb.y, acc[2][1]);
      acc[2][2] = fmaf(a.z, bb.z, acc[2][2]);
      acc[2][3] = fmaf(a.z, bb.w, acc[2][3]);
      acc[3][0] = fmaf(a.w, bb.x, acc[3][0]);
      acc[3][1] = fmaf(a.w, bb.y, acc[3][1]);
      acc[3][2] = fmaf(a.w, bb.z, acc[3][2]);
      acc[3][3] = fmaf(a.w, bb.w, acc[3][3]);
    }
  }
  float4 sv = *(const float4*)(sc + o0 + tx * 4);
  float4 bv = *(const float4*)(bi + o0 + tx * 4);
  if (EPI == EPI_MAX) {
    __syncthreads();
    float pm[4] = {-3.4e38f, -3.4e38f, -3.4e38f, -3.4e38f};
#pragma unroll
    for (int i = 0; i < 4; ++i) {
      pm[0] = fmaxf(pm[0], leaky(fmaf(acc[i][0], sv.x, bv.x)));
      pm[1] = fmaxf(pm[1], leaky(fmaf(acc[i][1], sv.y, bv.y)));
      pm[2] = fmaxf(pm[2], leaky(fmaf(acc[i][2], sv.z, bv.z)));
      pm[3] = fmaxf(pm[3], leaky(fmaf(acc[i][3], sv.w, bv.w)));
    }
    As[ty][tx * 4 + 0] = pm[0];
    As[ty][tx * 4 + 1] = pm[1];
    As[ty][tx * 4 + 2] = pm[2];
    As[ty][tx * 4 + 3] = pm[3];
    __syncthreads();
    if (t < 64) {
      float m = As[0][t];
#pragma unroll
      for (int g = 1; g < 16; ++g) m = fmaxf(m, As[g][t]);
      int b = row0 >> 12;
      atomicMax(&gmax[b * 1024 + o0 + t], encf(m));
    }
  } else {
    float4 ga = make_float4(0.f, 0.f, 0.f, 0.f);
    if (EPI == EPI_ADDG) ga = *(const float4*)(gadd + (row0 >> 12) * 256 + o0 + tx * 4);
#pragma unroll
    for (int i = 0; i < 4; ++i) {
      int r = row0 + ty * 4 + i;
      float4 ov;
      ov.x = leaky(fmaf(acc[i][0] + ga.x, sv.x, bv.x));
      ov.y = leaky(fmaf(acc[i][1] + ga.y, sv.y, bv.y));
      ov.z = leaky(fmaf(acc[i][2] + ga.z, sv.z, bv.z));
      ov.w = leaky(fmaf(acc[i][3] + ga.w, sv.w, bv.w));
      *(float4*)(outp + (size_t)r * ldo + o0 + tx * 4) = ov;
    }
  }
}

// ---------------- per-batch g . w8[:, :1024] ----------------
__global__ __launch_bounds__(256) void gdotk(const unsigned* __restrict__ gmax, const float* __restrict__ w8,
                                             float* __restrict__ gb8) {
  int wv = blockIdx.x * 4 + (threadIdx.x >> 6);
  int lane = threadIdx.x & 63;
  int b = wv >> 8, o = wv & 255;
  const float* wr = w8 + (size_t)o * 1216;
  const unsigned* gr = gmax + b * 1024;
  float acc = 0.f;
#pragma unroll
  for (int l = 0; l < 4; ++l) {
    int c = lane * 4 + l * 256;
    float4 wv4 = *(const float4*)(wr + c);
    acc = fmaf(decf(gr[c + 0]), wv4.x, acc);
    acc = fmaf(decf(gr[c + 1]), wv4.y, acc);
    acc = fmaf(decf(gr[c + 2]), wv4.z, acc);
    acc = fmaf(decf(gr[c + 3]), wv4.w, acc);
  }
#pragma unroll
  for (int off = 32; off >= 1; off >>= 1) acc += __shfl_down(acc, off);
  if (lane == 0) gb8[b * 256 + o] = acc;
}

// ---------------- final 128 -> 13 projection + transpose ----------------
__global__ __launch_bounds__(256) void outk(const float* __restrict__ h10, const float* __restrict__ w11,
                                            float* __restrict__ outp) {
  __shared__ float hs[64][132];
  __shared__ float wsm[13][128];
  int b = blockIdx.y, n0 = blockIdx.x * 64, t = threadIdx.x;
  for (int e = t; e < 13 * 128; e += 256) wsm[e >> 7][e & 127] = w11[e];
  const float* hb = h10 + ((size_t)(b * NPTS + n0)) * 128;
#pragma unroll
  for (int l = 0; l < 8; ++l) {
    int v = t + l * 256;
    int row = v >> 5, c4 = (v & 31) * 4;
    *(float4*)(&hs[row][c4]) = *(const float4*)(hb + (size_t)row * 128 + c4);
  }
  __syncthreads();
  for (int e = t; e < 13 * 64; e += 256) {
    int o = e >> 6, n = e & 63;
    float a0 = 0, a1 = 0, a2 = 0, a3 = 0;
#pragma unroll
    for (int c4 = 0; c4 < 32; ++c4) {
      float4 hv = *(const float4*)(&hs[n][c4 * 4]);
      const float* wr = &wsm[o][c4 * 4];
      a0 = fmaf(hv.x, wr[0], a0);
      a1 = fmaf(hv.y, wr[1], a1);
      a2 = fmaf(hv.z, wr[2], a2);
      a3 = fmaf(hv.w, wr[3], a3);
    }
    outp[((size_t)b * 13 + o) * NPTS + n0 + n] = (a0 + a1) + (a2 + a3);
  }
}

extern "C" void kernel_launch(void* const* d_in, const int* in_sizes, int n_in, void* d_out, int out_size, void* d_ws,
                              size_t ws_size, hipStream_t stream) {
  (void)in_sizes;
  (void)n_in;
  (void)out_size;
  (void)ws_size;
  const float* x = (const float*)d_in[0];
  const float* w1 = (const float*)d_in[1];
  const float* s1 = (const float*)d_in[2];
  const float* b1 = (const float*)d_in[3];
  const float* w2 = (const float*)d_in[4];
  const float* s2 = (const float*)d_in[5];
  const float* b2 = (const float*)d_in[6];
  const float* w3 = (const float*)d_in[7];
  const float* s3 = (const float*)d_in[8];
  const float* b3 = (const float*)d_in[9];
  const float* w4 = (const float*)d_in[10];
  const float* s4 = (const float*)d_in[11];
  const float* b4 = (const float*)d_in[12];
  const float* w5 = (const float*)d_in[13];
  const float* s5 = (const float*)d_in[14];
  const float* b5 = (const float*)d_in[15];
  const float* w6 = (const float*)d_in[16];
  const float* s6 = (const float*)d_in[17];
  const float* b6 = (const float*)d_in[18];
  const float* w8 = (const float*)d_in[19];
  const float* s8 = (const float*)d_in[20];
  const float* b8 = (const float*)d_in[21];
  const float* w9 = (const float*)d_in[22];
  const float* s9 = (const float*)d_in[23];
  const float* b9 = (const float*)d_in[24];
  const float* w10 = (const float*)d_in[25];
  const float* s10 = (const float*)d_in[26];
  const float* b10 = (const float*)d_in[27];
  const float* w11 = (const float*)d_in[28];

  float* ws = (float*)d_ws;
  size_t off = 0;
  int* idxb = (int*)ws;
  off += 655360;  // B*N*20
  float* x1 = ws + off;
  off += 2097152;
  float* x2 = ws + off;
  off += 2097152;
  float* x3 = ws + off;
  off += 2097152;
  float* nrm = ws + off;
  off += 131072;
  unsigned* gmax = (unsigned*)(ws + off);
  off += 8192;
  float* gb8 = ws + off;
  off += 2048;
  float* h8 = ws + off;
  off += 8388608;
  float* h9 = ws + off;
  off += 8388608;
  float* h10 = h8;  // reuse (h8 dead after l9)
  float* outp = (float*)d_out;

  knn_c3<<<dim3(64, BATCH), 256, 0, stream>>>(x, idxb);
  edgeconv<6, true, true><<<dim3(8192), 256, 0, stream>>>(x, idxb, w1, s1, b1, w2, s2, b2, x1);
  rownormk<<<dim3(128), 256, 0, stream>>>(x1, nrm);
  knn_c64<<<dim3(64, BATCH), 256, 0, stream>>>(x1, nrm, idxb);
  edgeconv<128, true, false><<<dim3(8192), 256, 0, stream>>>(x1, idxb, w3, s3, b3, w4, s4, b4, x2);
  rownormk<<<dim3(128), 256, 0, stream>>>(x2, nrm);
  knn_c64<<<dim3(64, BATCH), 256, 0, stream>>>(x2, nrm, idxb);
  edgeconv<128, false, false><<<dim3(8192), 256, 0, stream>>>(x2, idxb, w5, s5, b5, nullptr, nullptr, nullptr, x3);
  hipMemsetAsync(gmax, 0, 8192 * sizeof(unsigned), stream);
  gemmk<AM_CAT3, EPI_MAX><<<dim3(512, 16), 256, 0, stream>>>(x1, x2, x3, w6, 192, 192, s6, b6, nullptr, nullptr, 0,
                                                             gmax);
  gdotk<<<dim3(512), 256, 0, stream>>>(gmax, w8, gb8);
  gemmk<AM_CAT3, EPI_ADDG><<<dim3(512, 4), 256, 0, stream>>>(x1, x2, x3, w8 + 1024, 1216, 192, s8, b8, gb8, h8, 256,
                                                             nullptr);
  gemmk<AM_ROW, EPI_STORE><<<dim3(512, 4), 256, 0, stream>>>(h8, nullptr, nullptr, w9, 256, 256, s9, b9, nullptr, h9,
                                                             256, nullptr);
  gemmk<AM_ROW, EPI_STORE><<<dim3(512, 2), 256, 0, stream>>>(h9, nullptr, nullptr, w10, 256, 256, s10, b10, nullptr,
                                                             h10, 128, nullptr);
  outk<<<dim3(64, BATCH), 256, 0, stream>>>(h10, w11, outp);
}

// Round 3
// 2462.650 us; speedup vs baseline: 1.9054x; 1.2836x over previous
//
#include <hip/hip_runtime.h>
#include <cstdint>
#include <cstddef>

#define NPTS 4096
#define BATCH 8
#define KNB 20
#define SLOTS 18
#define FLUSH_THR 3

__device__ __forceinline__ float leaky(float v) { return v > 0.f ? v : 0.2f * v; }

__device__ __forceinline__ unsigned encf(float f) {
  unsigned u = __float_as_uint(f);
  return (u & 0x80000000u) ? ~u : (u | 0x80000000u);
}
__device__ __forceinline__ float decf(unsigned e) {
  unsigned u = (e & 0x80000000u) ? (e & 0x7FFFFFFFu) : ~e;
  return __uint_as_float(u);
}

// key = (~sortable(pd)) << 32 | j : smallest key = largest pd, ties -> smallest j
__device__ __forceinline__ unsigned long long mkkey(float pd, int j) {
  unsigned s = encf(pd);
  return (((unsigned long long)(~s)) << 32) | (unsigned)j;
}

// ---- top-20 insert, split float/int sorted list (descending pd) ----
// strict > keeps earlier-scanned (smaller j within a thread) on ties
__device__ __forceinline__ void tk_insert(float (&hf)[KNB], int (&hj)[KNB], float pd, int j) {
  if (pd > hf[KNB - 1]) {
    float cf = pd;
    int cj = j;
#pragma unroll
    for (int t = 0; t < KNB; ++t) {
      bool gt = cf > hf[t];
      float nf = gt ? cf : hf[t];
      int nj = gt ? cj : hj[t];
      cf = gt ? hf[t] : cf;
      cj = gt ? hj[t] : cj;
      hf[t] = nf;
      hj[t] = nj;
    }
  }
}

#define NEGINF (__int_as_float(0xff800000))

// lockstep flush of per-thread pending buffers into register top-20
__device__ __forceinline__ void flushbuf(const float* bpd, const unsigned short* bidx, int t, int& cnt, float& thr,
                                         float (&hf)[KNB], int (&hj)[KNB]) {
  for (int s = 0; s < SLOTS; ++s) {
    if (!__any(s < cnt)) break;
    if (s < cnt) {
      float pd = bpd[s * 256 + t];
      int j = bidx[s * 256 + t];
      tk_insert(hf, hj, pd, j);
    }
  }
  cnt = 0;
  thr = hf[KNB - 1];
}

#define APPEND(PD, J)                        \
  do {                                       \
    float _p = (PD);                         \
    if (_p > thr) {                          \
      bpd[cnt * 256 + t] = _p;               \
      bidx[cnt * 256 + t] = (unsigned short)(J); \
      ++cnt;                                 \
    }                                        \
  } while (0)

// shared final merge: threads 4q..4q+3 each hold sorted top-20; leader merges
__device__ __forceinline__ void merge4_out(unsigned long long* mb, int t, const float (&hf)[KNB], const int (&hj)[KNB],
                                           int* __restrict__ op_base) {
#pragma unroll
  for (int s = 0; s < KNB; ++s) mb[(size_t)t * KNB + s] = mkkey(hf[s], hj[s]);
  __syncthreads();
  if ((t & 3) == 0) {
    int p0 = 0, p1 = 0, p2 = 0, p3 = 0;
    const unsigned long long* l0 = mb + (size_t)(t + 0) * KNB;
    const unsigned long long* l1 = mb + (size_t)(t + 1) * KNB;
    const unsigned long long* l2 = mb + (size_t)(t + 2) * KNB;
    const unsigned long long* l3 = mb + (size_t)(t + 3) * KNB;
    for (int s = 0; s < KNB; ++s) {
      unsigned long long u0 = (p0 < KNB) ? l0[p0] : ~0ULL;
      unsigned long long u1 = (p1 < KNB) ? l1[p1] : ~0ULL;
      unsigned long long u2 = (p2 < KNB) ? l2[p2] : ~0ULL;
      unsigned long long u3 = (p3 < KNB) ? l3[p3] : ~0ULL;
      unsigned long long m01 = u0 < u1 ? u0 : u1;
      int s01 = u0 < u1 ? 0 : 1;
      unsigned long long m23 = u2 < u3 ? u2 : u3;
      int s23 = u2 < u3 ? 2 : 3;
      unsigned long long mm = m01 < m23 ? m01 : m23;
      int sm = m01 < m23 ? s01 : s23;
      p0 += (sm == 0);
      p1 += (sm == 1);
      p2 += (sm == 2);
      p3 += (sm == 3);
      op_base[s] = (int)(mm & 0xFFFFFFFFu);
    }
  }
}

// ---------------- kNN on 3-d input points (x is (B,3,N)) ----------------
// 64 queries/block (4 threads each), j tiled 1024 in LDS as float4(x,y,z,norm)
__global__ __launch_bounds__(256) void knn_c3(const float* __restrict__ x, int* __restrict__ idxo) {
  __shared__ float smem[11008];  // 44032B: f4t 4096 | bpd 4608 | bidx 2304f ; merge 40960B aliases base
  float4* f4t = (float4*)smem;
  float* bpd = smem + 4096;
  unsigned short* bidx = (unsigned short*)(smem + 8704);
  int b = blockIdx.y, t = threadIdx.x;
  int q = t >> 2, sub = t & 3;
  int i = blockIdx.x * 64 + q;
  const float* xb = x + (size_t)b * 3 * NPTS;
  float qx = xb[i], qy = xb[NPTS + i], qz = xb[2 * NPTS + i];
  float qn = fmaf(qz, qz, fmaf(qy, qy, qx * qx));
  float hf[KNB];
  int hj[KNB];
#pragma unroll
  for (int s = 0; s < KNB; ++s) {
    hf[s] = NEGINF;
    hj[s] = 0x7fffffff;
  }
  float thr = NEGINF;
  int cnt = 0;
  for (int j0 = 0; j0 < NPTS; j0 += 1024) {
    __syncthreads();
#pragma unroll
    for (int l = 0; l < 4; ++l) {
      int p = t + l * 256;
      float px = xb[j0 + p], py = xb[NPTS + j0 + p], pz = xb[2 * NPTS + j0 + p];
      float pn = fmaf(pz, pz, fmaf(py, py, px * px));
      f4t[p] = make_float4(px, py, pz, pn);
    }
    __syncthreads();
    for (int g = 0; g < 16; ++g) {
      if (__any(cnt >= FLUSH_THR)) flushbuf(bpd, bidx, t, cnt, thr, hf, hj);
#pragma unroll
      for (int s = 0; s < 16; ++s) {
        int jj = g * 64 + s * 4 + sub;
        float4 p = f4t[jj];
        float inner = fmaf(p.x, qx, fmaf(p.y, qy, p.z * qz));
        float pd = fmaf(2.0f, inner, -qn) - p.w;
        APPEND(pd, j0 + jj);
      }
    }
  }
  flushbuf(bpd, bidx, t, cnt, thr, hf, hj);
  __syncthreads();
  merge4_out((unsigned long long*)smem, t, hf, hj, idxo + ((size_t)(b * NPTS + i)) * KNB);
}

// ---------------- row squared norms for 64-wide features ----------------
__global__ __launch_bounds__(256) void rownormk(const float* __restrict__ f, float* __restrict__ nrm) {
  int r = blockIdx.x * 256 + threadIdx.x;
  const float* p = f + (size_t)r * 64;
  float a0 = 0, a1 = 0, a2 = 0, a3 = 0;
#pragma unroll
  for (int c4 = 0; c4 < 16; ++c4) {
    float4 v = *(const float4*)(p + c4 * 4);
    a0 = fmaf(v.x, v.x, a0);
    a1 = fmaf(v.y, v.y, a1);
    a2 = fmaf(v.z, v.z, a2);
    a3 = fmaf(v.w, v.w, a3);
  }
  nrm[r] = (a0 + a1) + (a2 + a3);
}

// ---------------- kNN on 64-wide features: tiled GEMM + append-buffer select ----------------
// block 256: Q-tile 64, J-tile 64; GEMM micro-tile 4q x 4j; selection 4 threads/query
__global__ __launch_bounds__(256) void knn64g(const float* __restrict__ feat, const float* __restrict__ nrm,
                                              int* __restrict__ idxo) {
  __shared__ float smem[15744];  // 62976B; see carve below; merge (40960B) aliases base after final flush
  float* Qs = smem;              // [64][68]   17408B
  float* Pp = smem + 4352;       // 16 panels x 260f (aliases pdt) 17408B region
  float* pdt = smem + 4352;      // [64][68]
  float* qn_s = smem + 8704;     // [64]
  float* pn_s = smem + 8768;     // [64]
  float* bpd = smem + 8832;      // [18][256]
  unsigned short* bidx = (unsigned short*)(smem + 13440);  // [18][256]
  int b = blockIdx.y, t = threadIdx.x;
  int q0 = blockIdx.x * 64;
  const float* fb = feat + (size_t)b * NPTS * 64;
  const float* nb = nrm + b * NPTS;
  int ty = t >> 4, tx = t & 15;
  int lq = t >> 2, seg = t & 3;  // selection role: query lq, j-segment seg

  // load Q-tile + qn
  {
    int r = t >> 2, cs = (t & 3) * 16;
#pragma unroll
    for (int s = 0; s < 4; ++s) {
      float4 v = *(const float4*)(fb + (size_t)(q0 + r) * 64 + cs + s * 4);
      *(float4*)(Qs + r * 68 + cs + s * 4) = v;
    }
    if (t < 64) qn_s[t] = nb[q0 + t];
  }

  float hf[KNB];
  int hj[KNB];
#pragma unroll
  for (int s = 0; s < KNB; ++s) {
    hf[s] = NEGINF;
    hj[s] = 0x7fffffff;
  }
  float thr = NEGINF;
  int cnt = 0;

  for (int j0 = 0; j0 < NPTS; j0 += 64) {
    __syncthreads();  // Qs ready / prev selection done
    // load P panels (k-major): panel p=j>>2 stride 260, elem [k*4 + (j&3)]
    {
      int j = t >> 2, cs = (t & 3) * 16;
      float* pan = Pp + (j >> 2) * 260 + (j & 3);
#pragma unroll
      for (int s = 0; s < 4; ++s) {
        float4 v = *(const float4*)(fb + (size_t)(j0 + j) * 64 + cs + s * 4);
        pan[(cs + s * 4 + 0) * 4] = v.x;
        pan[(cs + s * 4 + 1) * 4] = v.y;
        pan[(cs + s * 4 + 2) * 4] = v.z;
        pan[(cs + s * 4 + 3) * 4] = v.w;
      }
      if (t < 64) pn_s[t] = nb[j0 + t];
    }
    __syncthreads();
    // GEMM 64x64x64
    float acc[4][4];
#pragma unroll
    for (int i = 0; i < 4; ++i)
#pragma unroll
      for (int j = 0; j < 4; ++j) acc[i][j] = 0.f;
    const float* pb = Pp + tx * 260;
#pragma unroll 4
    for (int k4 = 0; k4 < 16; ++k4) {
      float4 Bf0 = *(const float4*)(pb + (k4 * 4 + 0) * 4);
      float4 Bf1 = *(const float4*)(pb + (k4 * 4 + 1) * 4);
      float4 Bf2 = *(const float4*)(pb + (k4 * 4 + 2) * 4);
      float4 Bf3 = *(const float4*)(pb + (k4 * 4 + 3) * 4);
#pragma unroll
      for (int i = 0; i < 4; ++i) {
        float4 Ai = *(const float4*)(Qs + (ty * 4 + i) * 68 + k4 * 4);
        acc[i][0] = fmaf(Ai.x, Bf0.x, acc[i][0]);
        acc[i][1] = fmaf(Ai.x, Bf0.y, acc[i][1]);
        acc[i][2] = fmaf(Ai.x, Bf0.z, acc[i][2]);
        acc[i][3] = fmaf(Ai.x, Bf0.w, acc[i][3]);
        acc[i][0] = fmaf(Ai.y, Bf1.x, acc[i][0]);
        acc[i][1] = fmaf(Ai.y, Bf1.y, acc[i][1]);
        acc[i][2] = fmaf(Ai.y, Bf1.z, acc[i][2]);
        acc[i][3] = fmaf(Ai.y, Bf1.w, acc[i][3]);
        acc[i][0] = fmaf(Ai.z, Bf2.x, acc[i][0]);
        acc[i][1] = fmaf(Ai.z, Bf2.y, acc[i][1]);
        acc[i][2] = fmaf(Ai.z, Bf2.z, acc[i][2]);
        acc[i][3] = fmaf(Ai.z, Bf2.w, acc[i][3]);
        acc[i][0] = fmaf(Ai.w, Bf3.x, acc[i][0]);
        acc[i][1] = fmaf(Ai.w, Bf3.y, acc[i][1]);
        acc[i][2] = fmaf(Ai.w, Bf3.z, acc[i][2]);
        acc[i][3] = fmaf(Ai.w, Bf3.w, acc[i][3]);
      }
    }
    __syncthreads();  // all Pp reads done; region becomes pdt
    // finalize pd and store transposed-access tile
#pragma unroll
    for (int i = 0; i < 4; ++i) {
      int qq = ty * 4 + i;
      float qn = qn_s[qq];
      float4 ov;
      ov.x = fmaf(2.f, acc[i][0], -qn) - pn_s[tx * 4 + 0];
      ov.y = fmaf(2.f, acc[i][1], -qn) - pn_s[tx * 4 + 1];
      ov.z = fmaf(2.f, acc[i][2], -qn) - pn_s[tx * 4 + 2];
      ov.w = fmaf(2.f, acc[i][3], -qn) - pn_s[tx * 4 + 3];
      *(float4*)(pdt + qq * 68 + tx * 4) = ov;
    }
    __syncthreads();
    // selection: 16 candidates per thread
    {
      const float* pr = pdt + lq * 68 + seg * 16;
      float4 pv0 = *(const float4*)(pr + 0);
      float4 pv1 = *(const float4*)(pr + 4);
      float4 pv2 = *(const float4*)(pr + 8);
      float4 pv3 = *(const float4*)(pr + 12);
      if (__any(cnt >= FLUSH_THR)) flushbuf(bpd, bidx, t, cnt, thr, hf, hj);
      int jb = j0 + seg * 16;
      APPEND(pv0.x, jb + 0);
      APPEND(pv0.y, jb + 1);
      APPEND(pv0.z, jb + 2);
      APPEND(pv0.w, jb + 3);
      APPEND(pv1.x, jb + 4);
      APPEND(pv1.y, jb + 5);
      APPEND(pv1.z, jb + 6);
      APPEND(pv1.w, jb + 7);
      APPEND(pv2.x, jb + 8);
      APPEND(pv2.y, jb + 9);
      APPEND(pv2.z, jb + 10);
      APPEND(pv2.w, jb + 11);
      APPEND(pv3.x, jb + 12);
      APPEND(pv3.y, jb + 13);
      APPEND(pv3.z, jb + 14);
      APPEND(pv3.w, jb + 15);
    }
  }
  flushbuf(bpd, bidx, t, cnt, thr, hf, hj);
  __syncthreads();
  merge4_out((unsigned long long*)smem, t, hf, hj, idxo + ((size_t)(b * NPTS + q0 + lq)) * KNB);
}

// ---------------- fused edge conv: gather->conv1(->conv2)->max over 20 ----------------
// block handles 4 queries = 80 edge rows; GEMM tile 80 x 64
template <int CIN, bool CONV2, bool CHMAJOR>
__global__ __launch_bounds__(256) void edgeconv(const float* __restrict__ src, const int* __restrict__ idx,
                                                const float* __restrict__ w1, const float* __restrict__ s1,
                                                const float* __restrict__ b1, const float* __restrict__ w2,
                                                const float* __restrict__ s2, const float* __restrict__ b2,
                                                float* __restrict__ outp) {
  constexpr int KS = (CIN < 16) ? CIN : 16;
  constexpr int HALF = CIN / 2;
  __shared__ float As[16][84];
  __shared__ float Ws[16][68];
  __shared__ float C1s[80][68];
  __shared__ float W4s[64][68];
  __shared__ float part[16][68];

  int t = threadIdx.x;
  int tx = t & 15, ty = t >> 4;
  int q0 = blockIdx.x * 4;
  int b = q0 >> 12;
  int n0 = q0 & (NPTS - 1);
  const int* idxb = idx + (size_t)q0 * KNB;

  if (CONV2) {
    for (int e = t; e < 64 * 64; e += 256) {
      int o = e >> 6, c = e & 63;
      W4s[c][o] = w2[e];  // w2[o*64+c]
    }
  }

  float acc1[5][4];
#pragma unroll
  for (int r = 0; r < 5; ++r)
#pragma unroll
    for (int j = 0; j < 4; ++j) acc1[r][j] = 0.f;

  for (int k0 = 0; k0 < CIN; k0 += KS) {
    __syncthreads();
    if (CHMAJOR) {  // src is (B,3,N)
      const float* sb = src + (size_t)b * 3 * NPTS;
      for (int e = t; e < 80 * KS; e += 256) {
        int row = e / KS, kk = e % KS;
        int nq = row / KNB, k20 = row % KNB;
        int n = n0 + nq;
        int jn2 = idxb[nq * KNB + k20];
        float v;
        if (kk < 3)
          v = sb[kk * NPTS + jn2] - sb[kk * NPTS + n];
        else
          v = sb[(kk - 3) * NPTS + n];
        As[kk][row] = v;
      }
    } else {  // src is (B,N,64)
      const float* sb = src + (size_t)b * NPTS * 64;
      for (int v4 = t; v4 < 80 * 4; v4 += 256) {
        int row = v4 >> 2, kq = v4 & 3;
        int c = k0 + kq * 4;
        int nq = row / KNB, k20 = row % KNB;
        int n = n0 + nq;
        float4 val;
        if (c < HALF) {
          int jn2 = idxb[nq * KNB + k20];
          float4 nbv = *(const float4*)(sb + (size_t)jn2 * 64 + c);
          float4 ctv = *(const float4*)(sb + (size_t)n * 64 + c);
          val = make_float4(nbv.x - ctv.x, nbv.y - ctv.y, nbv.z - ctv.z, nbv.w - ctv.w);
        } else {
          val = *(const float4*)(sb + (size_t)n * 64 + (c - HALF));
        }
        As[kq * 4 + 0][row] = val.x;
        As[kq * 4 + 1][row] = val.y;
        As[kq * 4 + 2][row] = val.z;
        As[kq * 4 + 3][row] = val.w;
      }
    }
    for (int e = t; e < 64 * KS; e += 256) {
      int o = e / KS, kk = e % KS;
      Ws[kk][o] = w1[o * CIN + k0 + kk];
    }
    __syncthreads();
#pragma unroll
    for (int kk = 0; kk < KS; ++kk) {
      float av[5];
      av[0] = As[kk][ty * 5 + 0];
      av[1] = As[kk][ty * 5 + 1];
      av[2] = As[kk][ty * 5 + 2];
      av[3] = As[kk][ty * 5 + 3];
      av[4] = As[kk][ty * 5 + 4];
      float4 bb = *(const float4*)&Ws[kk][tx * 4];
#pragma unroll
      for (int r = 0; r < 5; ++r) {
        acc1[r][0] = fmaf(av[r], bb.x, acc1[r][0]);
        acc1[r][1] = fmaf(av[r], bb.y, acc1[r][1]);
        acc1[r][2] = fmaf(av[r], bb.z, acc1[r][2]);
        acc1[r][3] = fmaf(av[r], bb.w, acc1[r][3]);
      }
    }
  }
  __syncthreads();
  float4 sv = *(const float4*)(s1 + tx * 4);
  float4 bv = *(const float4*)(b1 + tx * 4);
  float pmax[4];
#pragma unroll
  for (int j = 0; j < 4; ++j) pmax[j] = -3.4e38f;

  if (CONV2) {
#pragma unroll
    for (int r = 0; r < 5; ++r) {
      C1s[ty * 5 + r][tx * 4 + 0] = leaky(fmaf(acc1[r][0], sv.x, bv.x));
      C1s[ty * 5 + r][tx * 4 + 1] = leaky(fmaf(acc1[r][1], sv.y, bv.y));
      C1s[ty * 5 + r][tx * 4 + 2] = leaky(fmaf(acc1[r][2], sv.z, bv.z));
      C1s[ty * 5 + r][tx * 4 + 3] = leaky(fmaf(acc1[r][3], sv.w, bv.w));
    }
    __syncthreads();
    float acc2[5][4];
#pragma unroll
    for (int r = 0; r < 5; ++r)
#pragma unroll
      for (int j = 0; j < 4; ++j) acc2[r][j] = 0.f;
#pragma unroll
    for (int c = 0; c < 64; ++c) {
      float4 wb = *(const float4*)&W4s[c][tx * 4];
      float a0 = C1s[ty * 5 + 0][c];
      float a1 = C1s[ty * 5 + 1][c];
      float a2 = C1s[ty * 5 + 2][c];
      float a3 = C1s[ty * 5 + 3][c];
      float a4 = C1s[ty * 5 + 4][c];
      acc2[0][0] = fmaf(a0, wb.x, acc2[0][0]);
      acc2[0][1] = fmaf(a0, wb.y, acc2[0][1]);
      acc2[0][2] = fmaf(a0, wb.z, acc2[0][2]);
      acc2[0][3] = fmaf(a0, wb.w, acc2[0][3]);
      acc2[1][0] = fmaf(a1, wb.x, acc2[1][0]);
      acc2[1][1] = fmaf(a1, wb.y, acc2[1][1]);
      acc2[1][2] = fmaf(a1, wb.z, acc2[1][2]);
      acc2[1][3] = fmaf(a1, wb.w, acc2[1][3]);
      acc2[2][0] = fmaf(a2, wb.x, acc2[2][0]);
      acc2[2][1] = fmaf(a2, wb.y, acc2[2][1]);
      acc2[2][2] = fmaf(a2, wb.z, acc2[2][2]);
      acc2[2][3] = fmaf(a2, wb.w, acc2[2][3]);
      acc2[3][0] = fmaf(a3, wb.x, acc2[3][0]);
      acc2[3][1] = fmaf(a3, wb.y, acc2[3][1]);
      acc2[3][2] = fmaf(a3, wb.z, acc2[3][2]);
      acc2[3][3] = fmaf(a3, wb.w, acc2[3][3]);
      acc2[4][0] = fmaf(a4, wb.x, acc2[4][0]);
      acc2[4][1] = fmaf(a4, wb.y, acc2[4][1]);
      acc2[4][2] = fmaf(a4, wb.z, acc2[4][2]);
      acc2[4][3] = fmaf(a4, wb.w, acc2[4][3]);
    }
    float4 s2v = *(const float4*)(s2 + tx * 4);
    float4 b2v = *(const float4*)(b2 + tx * 4);
#pragma unroll
    for (int r = 0; r < 5; ++r) {
      pmax[0] = fmaxf(pmax[0], leaky(fmaf(acc2[r][0], s2v.x, b2v.x)));
      pmax[1] = fmaxf(pmax[1], leaky(fmaf(acc2[r][1], s2v.y, b2v.y)));
      pmax[2] = fmaxf(pmax[2], leaky(fmaf(acc2[r][2], s2v.z, b2v.z)));
      pmax[3] = fmaxf(pmax[3], leaky(fmaf(acc2[r][3], s2v.w, b2v.w)));
    }
  } else {
#pragma unroll
    for (int r = 0; r < 5; ++r) {
      pmax[0] = fmaxf(pmax[0], leaky(fmaf(acc1[r][0], sv.x, bv.x)));
      pmax[1] = fmaxf(pmax[1], leaky(fmaf(acc1[r][1], sv.y, bv.y)));
      pmax[2] = fmaxf(pmax[2], leaky(fmaf(acc1[r][2], sv.z, bv.z)));
      pmax[3] = fmaxf(pmax[3], leaky(fmaf(acc1[r][3], sv.w, bv.w)));
    }
  }
  part[ty][tx * 4 + 0] = pmax[0];
  part[ty][tx * 4 + 1] = pmax[1];
  part[ty][tx * 4 + 2] = pmax[2];
  part[ty][tx * 4 + 3] = pmax[3];
  __syncthreads();
  {
    int q = t >> 6, o = t & 63;
    float m = part[q * 4 + 0][o];
    m = fmaxf(m, part[q * 4 + 1][o]);
    m = fmaxf(m, part[q * 4 + 2][o]);
    m = fmaxf(m, part[q * 4 + 3][o]);
    outp[((size_t)(q0 + q)) * 64 + o] = m;
  }
}

// ---------------- generic tiled SGEMM: C = epi(A @ W^T) ----------------
#define AM_CAT3 0
#define AM_ROW 1
#define EPI_STORE 0
#define EPI_ADDG 1
#define EPI_MAX 2

template <int AMODE, int EPI>
__global__ __launch_bounds__(256) void gemmk(const float* __restrict__ a0, const float* __restrict__ a1,
                                             const float* __restrict__ a2, const float* __restrict__ w, int ldw,
                                             int Ksz, const float* __restrict__ sc, const float* __restrict__ bi,
                                             const float* __restrict__ gadd, float* __restrict__ outp, int ldo,
                                             unsigned* __restrict__ gmax) {
  __shared__ float As[16][68];
  __shared__ float Bs[16][68];
  int t = threadIdx.x, tx = t & 15, ty = t >> 4;
  int row0 = blockIdx.x * 64;
  int o0 = blockIdx.y * 64;
  float acc[4][4];
#pragma unroll
  for (int i = 0; i < 4; ++i)
#pragma unroll
    for (int j = 0; j < 4; ++j) acc[i][j] = 0.f;
  int arow = t >> 2;
  int ak4 = (t & 3) * 4;
  for (int k0 = 0; k0 < Ksz; k0 += 16) {
    __syncthreads();
    {
      int r = row0 + arow;
      int c = k0 + ak4;
      float4 v;
      if (AMODE == AM_CAT3) {
        const float* s = (c < 64) ? a0 : (c < 128 ? a1 : a2);
        v = *(const float4*)(s + (size_t)r * 64 + (c & 63));
      } else {
        v = *(const float4*)(a0 + (size_t)r * Ksz + c);
      }
      As[ak4 + 0][arow] = v.x;
      As[ak4 + 1][arow] = v.y;
      As[ak4 + 2][arow] = v.z;
      As[ak4 + 3][arow] = v.w;
      float4 wv = *(const float4*)(w + (size_t)(o0 + arow) * ldw + c);
      Bs[ak4 + 0][arow] = wv.x;
      Bs[ak4 + 1][arow] = wv.y;
      Bs[ak4 + 2][arow] = wv.z;
      Bs[ak4 + 3][arow] = wv.w;
    }
    __syncthreads();
#pragma unroll
    for (int kk = 0; kk < 16; ++kk) {
      float4 a = *(const float4*)&As[kk][ty * 4];
      float4 bb = *(const float4*)&Bs[kk][tx * 4];
      acc[0][0] = fmaf(a.x, bb.x, acc[0][0]);
      acc[0][1] = fmaf(a.x, bb.y, acc[0][1]);
      acc[0][2] = fmaf(a.x, bb.z, acc[0][2]);
      acc[0][3] = fmaf(a.x, bb.w, acc[0][3]);
      acc[1][0] = fmaf(a.y, bb.x, acc[1][0]);
      acc[1][1] = fmaf(a.y, bb.y, acc[1][1]);
      acc[1][2] = fmaf(a.y, bb.z, acc[1][2]);
      acc[1][3] = fmaf(a.y, bb.w, acc[1][3]);
      acc[2][0] = fmaf(a.z, bb.x, acc[2][0]);
      acc[2][1] = fmaf(a.z, bb.y, acc[2][1]);
      acc[2][2] = fmaf(a.z, bb.z, acc[2][2]);
      acc[2][3] = fmaf(a.z, bb.w, acc[2][3]);
      acc[3][0] = fmaf(a.w, bb.x, acc[3][0]);
      acc[3][1] = fmaf(a.w, bb.y, acc[3][1]);
      acc[3][2] = fmaf(a.w, bb.z, acc[3][2]);
      acc[3][3] = fmaf(a.w, bb.w, acc[3][3]);
    }
  }
  float4 sv = *(const float4*)(sc + o0 + tx * 4);
  float4 bv = *(const float4*)(bi + o0 + tx * 4);
  if (EPI == EPI_MAX) {
    __syncthreads();
    float pm[4] = {-3.4e38f, -3.4e38f, -3.4e38f, -3.4e38f};
#pragma unroll
    for (int i = 0; i < 4; ++i) {
      pm[0] = fmaxf(pm[0], leaky(fmaf(acc[i][0], sv.x, bv.x)));
      pm[1] = fmaxf(pm[1], leaky(fmaf(acc[i][1], sv.y, bv.y)));
      pm[2] = fmaxf(pm[2], leaky(fmaf(acc[i][2], sv.z, bv.z)));
      pm[3] = fmaxf(pm[3], leaky(fmaf(acc[i][3], sv.w, bv.w)));
    }
    As[ty][tx * 4 + 0] = pm[0];
    As[ty][tx * 4 + 1] = pm[1];
    As[ty][tx * 4 + 2] = pm[2];
    As[ty][tx * 4 + 3] = pm[3];
    __syncthreads();
    if (t < 64) {
      float m = As[0][t];
#pragma unroll
      for (int g = 1; g < 16; ++g) m = fmaxf(m, As[g][t]);
      int b = row0 >> 12;
      atomicMax(&gmax[b * 1024 + o0 + t], encf(m));
    }
  } else {
    float4 ga = make_float4(0.f, 0.f, 0.f, 0.f);
    if (EPI == EPI_ADDG) ga = *(const float4*)(gadd + (row0 >> 12) * 256 + o0 + tx * 4);
#pragma unroll
    for (int i = 0; i < 4; ++i) {
      int r = row0 + ty * 4 + i;
      float4 ov;
      ov.x = leaky(fmaf(acc[i][0] + ga.x, sv.x, bv.x));
      ov.y = leaky(fmaf(acc[i][1] + ga.y, sv.y, bv.y));
      ov.z = leaky(fmaf(acc[i][2] + ga.z, sv.z, bv.z));
      ov.w = leaky(fmaf(acc[i][3] + ga.w, sv.w, bv.w));
      *(float4*)(outp + (size_t)r * ldo + o0 + tx * 4) = ov;
    }
  }
}

// ---------------- per-batch g . w8[:, :1024] ----------------
__global__ __launch_bounds__(256) void gdotk(const unsigned* __restrict__ gmax, const float* __restrict__ w8,
                                             float* __restrict__ gb8) {
  int wv = blockIdx.x * 4 + (threadIdx.x >> 6);
  int lane = threadIdx.x & 63;
  int b = wv >> 8, o = wv & 255;
  const float* wr = w8 + (size_t)o * 1216;
  const unsigned* gr = gmax + b * 1024;
  float acc = 0.f;
#pragma unroll
  for (int l = 0; l < 4; ++l) {
    int c = lane * 4 + l * 256;
    float4 wv4 = *(const float4*)(wr + c);
    acc = fmaf(decf(gr[c + 0]), wv4.x, acc);
    acc = fmaf(decf(gr[c + 1]), wv4.y, acc);
    acc = fmaf(decf(gr[c + 2]), wv4.z, acc);
    acc = fmaf(decf(gr[c + 3]), wv4.w, acc);
  }
#pragma unroll
  for (int off = 32; off >= 1; off >>= 1) acc += __shfl_down(acc, off);
  if (lane == 0) gb8[b * 256 + o] = acc;
}

// ---------------- final 128 -> 13 projection + transpose ----------------
__global__ __launch_bounds__(256) void outk(const float* __restrict__ h10, const float* __restrict__ w11,
                                            float* __restrict__ outp) {
  __shared__ float hs[64][132];
  __shared__ float wsm[13][128];
  int b = blockIdx.y, n0 = blockIdx.x * 64, t = threadIdx.x;
  for (int e = t; e < 13 * 128; e += 256) wsm[e >> 7][e & 127] = w11[e];
  const float* hb = h10 + ((size_t)(b * NPTS + n0)) * 128;
#pragma unroll
  for (int l = 0; l < 8; ++l) {
    int v = t + l * 256;
    int row = v >> 5, c4 = (v & 31) * 4;
    *(float4*)(&hs[row][c4]) = *(const float4*)(hb + (size_t)row * 128 + c4);
  }
  __syncthreads();
  for (int e = t; e < 13 * 64; e += 256) {
    int o = e >> 6, n = e & 63;
    float a0 = 0, a1 = 0, a2 = 0, a3 = 0;
#pragma unroll
    for (int c4 = 0; c4 < 32; ++c4) {
      float4 hv = *(const float4*)(&hs[n][c4 * 4]);
      const float* wr = &wsm[o][c4 * 4];
      a0 = fmaf(hv.x, wr[0], a0);
      a1 = fmaf(hv.y, wr[1], a1);
      a2 = fmaf(hv.z, wr[2], a2);
      a3 = fmaf(hv.w, wr[3], a3);
    }
    outp[((size_t)b * 13 + o) * NPTS + n0 + n] = (a0 + a1) + (a2 + a3);
  }
}

extern "C" void kernel_launch(void* const* d_in, const int* in_sizes, int n_in, void* d_out, int out_size, void* d_ws,
                              size_t ws_size, hipStream_t stream) {
  (void)in_sizes;
  (void)n_in;
  (void)out_size;
  (void)ws_size;
  const float* x = (const float*)d_in[0];
  const float* w1 = (const float*)d_in[1];
  const float* s1 = (const float*)d_in[2];
  const float* b1 = (const float*)d_in[3];
  const float* w2 = (const float*)d_in[4];
  const float* s2 = (const float*)d_in[5];
  const float* b2 = (const float*)d_in[6];
  const float* w3 = (const float*)d_in[7];
  const float* s3 = (const float*)d_in[8];
  const float* b3 = (const float*)d_in[9];
  const float* w4 = (const float*)d_in[10];
  const float* s4 = (const float*)d_in[11];
  const float* b4 = (const float*)d_in[12];
  const float* w5 = (const float*)d_in[13];
  const float* s5 = (const float*)d_in[14];
  const float* b5 = (const float*)d_in[15];
  const float* w6 = (const float*)d_in[16];
  const float* s6 = (const float*)d_in[17];
  const float* b6 = (const float*)d_in[18];
  const float* w8 = (const float*)d_in[19];
  const float* s8 = (const float*)d_in[20];
  const float* b8 = (const float*)d_in[21];
  const float* w9 = (const float*)d_in[22];
  const float* s9 = (const float*)d_in[23];
  const float* b9 = (const float*)d_in[24];
  const float* w10 = (const float*)d_in[25];
  const float* s10 = (const float*)d_in[26];
  const float* b10 = (const float*)d_in[27];
  const float* w11 = (const float*)d_in[28];

  float* ws = (float*)d_ws;
  size_t off = 0;
  int* idxb = (int*)ws;
  off += 655360;  // B*N*20
  float* x1 = ws + off;
  off += 2097152;
  float* x2 = ws + off;
  off += 2097152;
  float* x3 = ws + off;
  off += 2097152;
  float* nrm = ws + off;
  off += 131072;
  unsigned* gmax = (unsigned*)(ws + off);
  off += 8192;
  float* gb8 = ws + off;
  off += 2048;
  float* h8 = ws + off;
  off += 8388608;
  float* h9 = ws + off;
  off += 8388608;
  float* h10 = h8;  // reuse (h8 dead after l9)
  float* outp = (float*)d_out;

  knn_c3<<<dim3(64, BATCH), 256, 0, stream>>>(x, idxb);
  edgeconv<6, true, true><<<dim3(8192), 256, 0, stream>>>(x, idxb, w1, s1, b1, w2, s2, b2, x1);
  rownormk<<<dim3(128), 256, 0, stream>>>(x1, nrm);
  knn64g<<<dim3(64, BATCH), 256, 0, stream>>>(x1, nrm, idxb);
  edgeconv<128, true, false><<<dim3(8192), 256, 0, stream>>>(x1, idxb, w3, s3, b3, w4, s4, b4, x2);
  rownormk<<<dim3(128), 256, 0, stream>>>(x2, nrm);
  knn64g<<<dim3(64, BATCH), 256, 0, stream>>>(x2, nrm, idxb);
  edgeconv<128, false, false><<<dim3(8192), 256, 0, stream>>>(x2, idxb, w5, s5, b5, nullptr, nullptr, nullptr, x3);
  hipMemsetAsync(gmax, 0, 8192 * sizeof(unsigned), stream);
  gemmk<AM_CAT3, EPI_MAX><<<dim3(512, 16), 256, 0, stream>>>(x1, x2, x3, w6, 192, 192, s6, b6, nullptr, nullptr, 0,
                                                             gmax);
  gdotk<<<dim3(512), 256, 0, stream>>>(gmax, w8, gb8);
  gemmk<AM_CAT3, EPI_ADDG><<<dim3(512, 4), 256, 0, stream>>>(x1, x2, x3, w8 + 1024, 1216, 192, s8, b8, gb8, h8, 256,
                                                             nullptr);
  gemmk<AM_ROW, EPI_STORE><<<dim3(512, 4), 256, 0, stream>>>(h8, nullptr, nullptr, w9, 256, 256, s9, b9, nullptr, h9,
                                                             256, nullptr);
  gemmk<AM_ROW, EPI_STORE><<<dim3(512, 2), 256, 0, stream>>>(h9, nullptr, nullptr, w10, 256, 256, s10, b10, nullptr,
                                                             h10, 128, nullptr);
  outk<<<dim3(64, BATCH), 256, 0, stream>>>(h10, w11, outp);
}

// Round 6
// 2094.495 us; speedup vs baseline: 2.2403x; 1.1758x over previous
//
#include <hip/hip_runtime.h>
#include <cstdint>
#include <cstddef>

#define NPTS 4096
#define BATCH 8
#define KNB 20
#define SLOTS 12

__device__ __forceinline__ float leaky(float v) { return v > 0.f ? v : 0.2f * v; }

__device__ __forceinline__ unsigned encf(float f) {
  unsigned u = __float_as_uint(f);
  return (u & 0x80000000u) ? ~u : (u | 0x80000000u);
}
__device__ __forceinline__ float decf(unsigned e) {
  unsigned u = (e & 0x80000000u) ? (e & 0x7FFFFFFFu) : ~e;
  return __uint_as_float(u);
}

// key = (~sortable(pd)) << 32 | j : smallest key = largest pd, ties -> smallest j
__device__ __forceinline__ unsigned long long mkkey(float pd, int j) {
  unsigned s = encf(pd);
  return (((unsigned long long)(~s)) << 32) | (unsigned)j;
}

#define NEGINF (__int_as_float(0xff800000))

// ---- top-20 insert, split float/int sorted list (descending pd) ----
__device__ __forceinline__ void tk_insert(float (&hf)[KNB], int (&hj)[KNB], float pd, int j) {
  if (pd > hf[KNB - 1]) {
    float cf = pd;
    int cj = j;
#pragma unroll
    for (int t = 0; t < KNB; ++t) {
      bool gt = cf > hf[t];
      float nf = gt ? cf : hf[t];
      int nj = gt ? cj : hj[t];
      cf = gt ? hf[t] : cf;
      cj = gt ? hj[t] : cj;
      hf[t] = nf;
      hj[t] = nj;
    }
  }
}

// lockstep flush of per-thread pending buffers into register top-20
__device__ __forceinline__ void flushbuf(const float* bpd, const unsigned short* bidx, int t, int stride, int& cnt,
                                         float& thr, float (&hf)[KNB], int (&hj)[KNB]) {
  for (int s = 0; s < SLOTS; ++s) {
    if (!__any(s < cnt)) break;
    if (s < cnt) {
      float pd = bpd[s * stride + t];
      int j = bidx[s * stride + t];
      tk_insert(hf, hj, pd, j);
    }
  }
  cnt = 0;
  thr = hf[KNB - 1];
}

#define APPEND(PD, J, STRIDE)                    \
  do {                                           \
    float _p = (PD);                             \
    if (_p > thr) {                              \
      bpd[cnt * (STRIDE) + t] = _p;              \
      bidx[cnt * (STRIDE) + t] = (unsigned short)(J); \
      ++cnt;                                     \
    }                                            \
  } while (0)

// ---------------- kNN on 3-d input points (x is (B,3,N)) ----------------
__global__ __launch_bounds__(256) void knn_c3(const float* __restrict__ x, int* __restrict__ idxo) {
  __shared__ __align__(16) float smem[11008];
  float4* f4t = (float4*)smem;
  float* bpd = smem + 4096;
  unsigned short* bidx = (unsigned short*)(smem + 8704);
  int b = blockIdx.y, t = threadIdx.x;
  int q = t >> 2, sub = t & 3;
  int i = blockIdx.x * 64 + q;
  const float* xb = x + (size_t)b * 3 * NPTS;
  float qx = xb[i], qy = xb[NPTS + i], qz = xb[2 * NPTS + i];
  float qn = fmaf(qz, qz, fmaf(qy, qy, qx * qx));
  float hf[KNB];
  int hj[KNB];
#pragma unroll
  for (int s = 0; s < KNB; ++s) {
    hf[s] = NEGINF;
    hj[s] = 0x7fffffff;
  }
  float thr = NEGINF;
  int cnt = 0;
  for (int j0 = 0; j0 < NPTS; j0 += 1024) {
    __syncthreads();
#pragma unroll
    for (int l = 0; l < 4; ++l) {
      int p = t + l * 256;
      float px = xb[j0 + p], py = xb[NPTS + j0 + p], pz = xb[2 * NPTS + j0 + p];
      float pn = fmaf(pz, pz, fmaf(py, py, px * px));
      f4t[p] = make_float4(px, py, pz, pn);
    }
    __syncthreads();
    // 8 candidates per flush-check: cnt <= 4 + 8 = 12 = SLOTS (no overflow)
    for (int g = 0; g < 32; ++g) {
      if (__any(cnt >= 5)) flushbuf(bpd, bidx, t, 256, cnt, thr, hf, hj);
#pragma unroll
      for (int s = 0; s < 8; ++s) {
        int jj = g * 32 + s * 4 + sub;
        float4 p = f4t[jj];
        float inner = fmaf(p.x, qx, fmaf(p.y, qy, p.z * qz));
        float pd = fmaf(2.0f, inner, -qn) - p.w;
        APPEND(pd, j0 + jj, 256);
      }
    }
  }
  flushbuf(bpd, bidx, t, 256, cnt, thr, hf, hj);
  __syncthreads();
  unsigned long long* mb = (unsigned long long*)smem;
#pragma unroll
  for (int s = 0; s < KNB; ++s) mb[(size_t)t * KNB + s] = mkkey(hf[s], hj[s]);
  __syncthreads();
  if (sub == 0) {
    int p0 = 0, p1 = 0, p2 = 0, p3 = 0;
    const unsigned long long* l0 = mb + (size_t)(t + 0) * KNB;
    const unsigned long long* l1 = mb + (size_t)(t + 1) * KNB;
    const unsigned long long* l2 = mb + (size_t)(t + 2) * KNB;
    const unsigned long long* l3 = mb + (size_t)(t + 3) * KNB;
    int* op = idxo + ((size_t)(b * NPTS + i)) * KNB;
    for (int s = 0; s < KNB; ++s) {
      unsigned long long u0 = (p0 < KNB) ? l0[p0] : ~0ULL;
      unsigned long long u1 = (p1 < KNB) ? l1[p1] : ~0ULL;
      unsigned long long u2 = (p2 < KNB) ? l2[p2] : ~0ULL;
      unsigned long long u3 = (p3 < KNB) ? l3[p3] : ~0ULL;
      unsigned long long m01 = u0 < u1 ? u0 : u1;
      int s01 = u0 < u1 ? 0 : 1;
      unsigned long long m23 = u2 < u3 ? u2 : u3;
      int s23 = u2 < u3 ? 2 : 3;
      unsigned long long mm = m01 < m23 ? m01 : m23;
      int sm = m01 < m23 ? s01 : s23;
      p0 += (sm == 0);
      p1 += (sm == 1);
      p2 += (sm == 2);
      p3 += (sm == 3);
      op[s] = (int)(mm & 0xFFFFFFFFu);
    }
  }
}

// ---------------- row squared norms ----------------
__global__ __launch_bounds__(256) void rownormk(const float* __restrict__ f, float* __restrict__ nrm) {
  int r = blockIdx.x * 256 + threadIdx.x;
  const float* p = f + (size_t)r * 64;
  float a0 = 0, a1 = 0, a2 = 0, a3 = 0;
#pragma unroll
  for (int c4 = 0; c4 < 16; ++c4) {
    float4 v = *(const float4*)(p + c4 * 4);
    a0 = fmaf(v.x, v.x, a0);
    a1 = fmaf(v.y, v.y, a1);
    a2 = fmaf(v.z, v.z, a2);
    a3 = fmaf(v.w, v.w, a3);
  }
  nrm[r] = (a0 + a1) + (a2 + a3);
}

// ---------------- kNN-64: 64q x 128j tile, 8x8 micro, k-major LDS ----------------
// 128 threads (2 waves). pd' = 2*dot - pn (qn dropped: constant per query, order-invariant)
__global__ __launch_bounds__(128) void knn64g(const float* __restrict__ feat, const float* __restrict__ nrm,
                                              int* __restrict__ idxo) {
  __shared__ __align__(16) float smem[15360];  // 61440 B
  float* Qt = smem;                            // [64k][68] k-major Q
  float* Pt = smem + 4352;                     // [32k][132] k-major P (per k-pass)
  float* pdt = smem + 8576;                    // [64][68] selection tile (xor-swizzled)
  float* pn_s = smem + 12928;                  // [128]
  float* bpd = smem + 13056;                   // [SLOTS][128]
  unsigned short* bidx = (unsigned short*)(smem + 13056 + SLOTS * 128);
  int b = blockIdx.y, t = threadIdx.x;
  int q0 = blockIdx.x * 64;
  const float* fb = feat + (size_t)b * NPTS * 64;
  const float* nb = nrm + b * NPTS;
  int tx = t & 15, ty = t >> 4;  // GEMM roles: j cols {tx*4, 64+tx*4}; q rows {ty*4, 32+ty*4}

  // stage Q k-major
  {
    int q = t >> 1, kh = (t & 1) * 32;
#pragma unroll
    for (int s = 0; s < 8; ++s) {
      float4 v = *(const float4*)(fb + (size_t)(q0 + q) * 64 + kh + s * 4);
      Qt[(kh + s * 4 + 0) * 68 + q] = v.x;
      Qt[(kh + s * 4 + 1) * 68 + q] = v.y;
      Qt[(kh + s * 4 + 2) * 68 + q] = v.z;
      Qt[(kh + s * 4 + 3) * 68 + q] = v.w;
    }
  }
  float hf[KNB];
  int hj[KNB];
#pragma unroll
  for (int s = 0; s < KNB; ++s) {
    hf[s] = NEGINF;
    hj[s] = 0x7fffffff;
  }
  float thr = NEGINF;
  int cnt = 0;

  for (int j0 = 0; j0 < NPTS; j0 += 128) {
    float acc[8][8];
#pragma unroll
    for (int i = 0; i < 8; ++i)
#pragma unroll
      for (int j = 0; j < 8; ++j) acc[i][j] = 0.f;

    for (int kp = 0; kp < 2; ++kp) {
      __syncthreads();  // prev Pt reads / prev-tile selection done
      int kg = kp * 32;
#pragma unroll
      for (int s = 0; s < 8; ++s) {
        int j = (t >> 2) + (s & 3) * 32;
        int c = (t & 3) * 8 + (s >> 2) * 4;
        float4 v = *(const float4*)(fb + (size_t)(j0 + j) * 64 + kg + c);
        Pt[(c + 0) * 132 + j] = v.x;
        Pt[(c + 1) * 132 + j] = v.y;
        Pt[(c + 2) * 132 + j] = v.z;
        Pt[(c + 3) * 132 + j] = v.w;
      }
      if (kp == 0) pn_s[t] = nb[j0 + t];
      __syncthreads();
#pragma unroll 4
      for (int k = 0; k < 32; ++k) {
        float4 A0 = *(const float4*)(Qt + (kg + k) * 68 + ty * 4);
        float4 A1 = *(const float4*)(Qt + (kg + k) * 68 + 32 + ty * 4);
        float4 B0 = *(const float4*)(Pt + k * 132 + tx * 4);
        float4 B1 = *(const float4*)(Pt + k * 132 + 64 + tx * 4);
        float Aa[8] = {A0.x, A0.y, A0.z, A0.w, A1.x, A1.y, A1.z, A1.w};
        float Bb[8] = {B0.x, B0.y, B0.z, B0.w, B1.x, B1.y, B1.z, B1.w};
#pragma unroll
        for (int i = 0; i < 8; ++i)
#pragma unroll
          for (int j = 0; j < 8; ++j) acc[i][j] = fmaf(Aa[i], Bb[j], acc[i][j]);
      }
    }
    // selection over two 64-j halves
#pragma unroll
    for (int jh = 0; jh < 2; ++jh) {
      __syncthreads();
      float4 pnv = *(const float4*)(pn_s + jh * 64 + tx * 4);
#pragma unroll
      for (int qa = 0; qa < 2; ++qa)
#pragma unroll
        for (int qi = 0; qi < 4; ++qi) {
          int row = qa * 32 + ty * 4 + qi;
          int key = (row >> 3) & 3;
          float4 v;
          v.x = fmaf(2.f, acc[qa * 4 + qi][jh * 4 + 0], -pnv.x);
          v.y = fmaf(2.f, acc[qa * 4 + qi][jh * 4 + 1], -pnv.y);
          v.z = fmaf(2.f, acc[qa * 4 + qi][jh * 4 + 2], -pnv.z);
          v.w = fmaf(2.f, acc[qa * 4 + qi][jh * 4 + 3], -pnv.w);
          *(float4*)(pdt + row * 68 + ((tx * 4) ^ (key << 2))) = v;
        }
      __syncthreads();
      {
        int lq = t >> 1, seg = t & 1;
        int key = (lq >> 3) & 3;
        const float* pr = pdt + lq * 68;
        int jb = j0 + jh * 64 + seg * 32;
#pragma unroll
        for (int ep = 0; ep < 4; ++ep) {
          if (__any(cnt >= 5)) flushbuf(bpd, bidx, t, 128, cnt, thr, hf, hj);
#pragma unroll
          for (int e2 = 0; e2 < 2; ++e2) {
            int e = ep * 2 + e2;
            float4 pv = *(const float4*)(pr + ((seg * 32 + e * 4) ^ (key << 2)));
            APPEND(pv.x, jb + e * 4 + 0, 128);
            APPEND(pv.y, jb + e * 4 + 1, 128);
            APPEND(pv.z, jb + e * 4 + 2, 128);
            APPEND(pv.w, jb + e * 4 + 3, 128);
          }
        }
      }
    }
  }
  flushbuf(bpd, bidx, t, 128, cnt, thr, hf, hj);
  __syncthreads();
  unsigned long long* mb = (unsigned long long*)smem;
#pragma unroll
  for (int s = 0; s < KNB; ++s) mb[(size_t)t * KNB + s] = mkkey(hf[s], hj[s]);
  __syncthreads();
  if ((t & 1) == 0) {
    int p0 = 0, p1 = 0;
    const unsigned long long* l0 = mb + (size_t)(t + 0) * KNB;
    const unsigned long long* l1 = mb + (size_t)(t + 1) * KNB;
    int* op = idxo + ((size_t)(b * NPTS + q0 + (t >> 1))) * KNB;
    for (int s = 0; s < KNB; ++s) {
      unsigned long long u0 = (p0 < KNB) ? l0[p0] : ~0ULL;
      unsigned long long u1 = (p1 < KNB) ? l1[p1] : ~0ULL;
      bool t0 = u0 < u1;
      unsigned long long mm = t0 ? u0 : u1;
      p0 += t0;
      p1 += !t0;
      op[s] = (int)(mm & 0xFFFFFFFFu);
    }
  }
}

// ---------------- U/V for layer 1 (CIN=6, K=3) ----------------
__global__ __launch_bounds__(256) void uv3(const float* __restrict__ x, const float* __restrict__ w1,
                                           float* __restrict__ U, float* __restrict__ V) {
  __shared__ float xs[64][3];
  __shared__ float wa[192], wv[192];
  int t = threadIdx.x;
  int g0 = blockIdx.x * 64;
  if (t < 192) {
    int o = t / 3, c = t % 3;
    float a = w1[o * 6 + c];
    wa[t] = a;
    wv[t] = w1[o * 6 + 3 + c] - a;
  }
  if (t < 192) {
    int c = t >> 6, i = t & 63;
    int b = g0 >> 12, n0 = g0 & (NPTS - 1);
    xs[i][c] = x[(size_t)b * 3 * NPTS + c * NPTS + n0 + i];
  }
  __syncthreads();
  int nl = t >> 2, cq = t & 3;
  float x0 = xs[nl][0], x1v = xs[nl][1], x2v = xs[nl][2];
  size_t ob = (size_t)(g0 + nl) * 64 + cq * 16;
#pragma unroll
  for (int s = 0; s < 4; ++s) {
    float4 u, v;
    float* up = (float*)&u;
    float* vp = (float*)&v;
#pragma unroll
    for (int e = 0; e < 4; ++e) {
      int o = cq * 16 + s * 4 + e;
      up[e] = fmaf(x2v, wa[o * 3 + 2], fmaf(x1v, wa[o * 3 + 1], x0 * wa[o * 3]));
      vp[e] = fmaf(x2v, wv[o * 3 + 2], fmaf(x1v, wv[o * 3 + 1], x0 * wv[o * 3]));
    }
    *(float4*)(U + ob + s * 4) = u;
    *(float4*)(V + ob + s * 4) = v;
  }
}

// ---------------- fused gather + conv2 + max20: out[i] = max_k leaky((E1 @ w2^T)*s2+b2) ----------------
// E1[edge] = leaky((U[j]+V[i])*s1+b1); 8 queries (160 edges) per block
// NOTE: idx holds batch-LOCAL j (0..4095) -> U must be indexed with batch base!
__global__ __launch_bounds__(256) void edgemax2(const float* __restrict__ U, const float* __restrict__ V,
                                                const int* __restrict__ idx, const float* __restrict__ s1,
                                                const float* __restrict__ b1, const float* __restrict__ w2,
                                                const float* __restrict__ s2, const float* __restrict__ b2,
                                                float* __restrict__ outp) {
  __shared__ __align__(16) float E1s[160][68];
  __shared__ float W4s[64][68];
  __shared__ int jrow[160];
  int t = threadIdx.x, tx = t & 15, ty = t >> 4;
  int q0 = blockIdx.x * 8;
  const float* Ub = U + (((size_t)(q0 >> 12)) << 12) * 64;  // batch base (4096 rows/batch)
  for (int e = t; e < 4096; e += 256) W4s[e & 63][e >> 6] = w2[e];
  if (t < 160) jrow[t] = idx[(size_t)q0 * KNB + t];
  __syncthreads();
  for (int v = t; v < 160 * 16; v += 256) {
    int row = v >> 4, cq = (v & 15) * 4;
    int q = (row * 205) >> 12;  // row/20
    int j = jrow[row];
    float4 uv = *(const float4*)(Ub + (size_t)j * 64 + cq);
    float4 vv = *(const float4*)(V + ((size_t)(q0 + q)) * 64 + cq);
    float4 s1v = *(const float4*)(s1 + cq);
    float4 b1v = *(const float4*)(b1 + cq);
    float4 ev;
    ev.x = leaky(fmaf(uv.x + vv.x, s1v.x, b1v.x));
    ev.y = leaky(fmaf(uv.y + vv.y, s1v.y, b1v.y));
    ev.z = leaky(fmaf(uv.z + vv.z, s1v.z, b1v.z));
    ev.w = leaky(fmaf(uv.w + vv.w, s1v.w, b1v.w));
    *(float4*)(&E1s[row][cq]) = ev;
  }
  __syncthreads();
  float acc[10][4];
#pragma unroll
  for (int r = 0; r < 10; ++r)
#pragma unroll
    for (int j = 0; j < 4; ++j) acc[r][j] = 0.f;
#pragma unroll 2
  for (int k4 = 0; k4 < 16; ++k4) {
    float4 B0 = *(const float4*)(&W4s[k4 * 4 + 0][tx * 4]);
    float4 B1 = *(const float4*)(&W4s[k4 * 4 + 1][tx * 4]);
    float4 B2 = *(const float4*)(&W4s[k4 * 4 + 2][tx * 4]);
    float4 B3 = *(const float4*)(&W4s[k4 * 4 + 3][tx * 4]);
#pragma unroll
    for (int r = 0; r < 10; ++r) {
      float4 a = *(const float4*)(&E1s[ty * 10 + r][k4 * 4]);
      acc[r][0] = fmaf(a.w, B3.x, fmaf(a.z, B2.x, fmaf(a.y, B1.x, fmaf(a.x, B0.x, acc[r][0]))));
      acc[r][1] = fmaf(a.w, B3.y, fmaf(a.z, B2.y, fmaf(a.y, B1.y, fmaf(a.x, B0.y, acc[r][1]))));
      acc[r][2] = fmaf(a.w, B3.z, fmaf(a.z, B2.z, fmaf(a.y, B1.z, fmaf(a.x, B0.z, acc[r][2]))));
      acc[r][3] = fmaf(a.w, B3.w, fmaf(a.z, B2.w, fmaf(a.y, B1.w, fmaf(a.x, B0.w, acc[r][3]))));
    }
  }
  __syncthreads();
  float* part = (float*)E1s;  // [16][68] alias
  float4 s2v = *(const float4*)(s2 + tx * 4);
  float4 b2v = *(const float4*)(b2 + tx * 4);
  float pm[4] = {-3.4e38f, -3.4e38f, -3.4e38f, -3.4e38f};
#pragma unroll
  for (int r = 0; r < 10; ++r) {
    pm[0] = fmaxf(pm[0], leaky(fmaf(acc[r][0], s2v.x, b2v.x)));
    pm[1] = fmaxf(pm[1], leaky(fmaf(acc[r][1], s2v.y, b2v.y)));
    pm[2] = fmaxf(pm[2], leaky(fmaf(acc[r][2], s2v.z, b2v.z)));
    pm[3] = fmaxf(pm[3], leaky(fmaf(acc[r][3], s2v.w, b2v.w)));
  }
  part[ty * 68 + tx * 4 + 0] = pm[0];
  part[ty * 68 + tx * 4 + 1] = pm[1];
  part[ty * 68 + tx * 4 + 2] = pm[2];
  part[ty * 68 + tx * 4 + 3] = pm[3];
  __syncthreads();
  {
    int e = t;  // 256 of 512 outputs, twice
#pragma unroll
    for (int l = 0; l < 2; ++l) {
      int q = e >> 6, o = e & 63;
      float m = fmaxf(part[(2 * q) * 68 + o], part[(2 * q + 1) * 68 + o]);
      outp[((size_t)(q0 + q)) * 64 + o] = m;
      e += 256;
    }
  }
}

// ---------------- layer5: out[i] = max_j leaky((U[j]+V[i])*s+b) ----------------
// NOTE: j batch-LOCAL -> U batch base
__global__ __launch_bounds__(256) void edgemax1(const float* __restrict__ U, const float* __restrict__ V,
                                                const int* __restrict__ idx, const float* __restrict__ s1,
                                                const float* __restrict__ b1, float* __restrict__ outp) {
  int t = threadIdx.x;
  int g = blockIdx.x * 64 + (t >> 2);
  const float* Ub = U + (((size_t)(g >> 12)) << 12) * 64;  // batch base
  int cs = (t & 3) * 16;
  const float* vr = V + (size_t)g * 64 + cs;
  float4 v0 = *(const float4*)(vr + 0), v1 = *(const float4*)(vr + 4);
  float4 v2 = *(const float4*)(vr + 8), v3 = *(const float4*)(vr + 12);
  float4 s0 = *(const float4*)(s1 + cs + 0), s1v = *(const float4*)(s1 + cs + 4);
  float4 s2v = *(const float4*)(s1 + cs + 8), s3v = *(const float4*)(s1 + cs + 12);
  float4 b0 = *(const float4*)(b1 + cs + 0), b1v = *(const float4*)(b1 + cs + 4);
  float4 b2v = *(const float4*)(b1 + cs + 8), b3v = *(const float4*)(b1 + cs + 12);
  float4 m0 = make_float4(-3.4e38f, -3.4e38f, -3.4e38f, -3.4e38f), m1 = m0, m2 = m0, m3 = m0;
  const int* ib = idx + (size_t)g * KNB;
  for (int k = 0; k < KNB; ++k) {
    int j = ib[k];
    const float* ur = Ub + (size_t)j * 64 + cs;
    float4 u0 = *(const float4*)(ur + 0), u1 = *(const float4*)(ur + 4);
    float4 u2 = *(const float4*)(ur + 8), u3 = *(const float4*)(ur + 12);
    m0.x = fmaxf(m0.x, leaky(fmaf(u0.x + v0.x, s0.x, b0.x)));
    m0.y = fmaxf(m0.y, leaky(fmaf(u0.y + v0.y, s0.y, b0.y)));
    m0.z = fmaxf(m0.z, leaky(fmaf(u0.z + v0.z, s0.z, b0.z)));
    m0.w = fmaxf(m0.w, leaky(fmaf(u0.w + v0.w, s0.w, b0.w)));
    m1.x = fmaxf(m1.x, leaky(fmaf(u1.x + v1.x, s1v.x, b1v.x)));
    m1.y = fmaxf(m1.y, leaky(fmaf(u1.y + v1.y, s1v.y, b1v.y)));
    m1.z = fmaxf(m1.z, leaky(fmaf(u1.z + v1.z, s1v.z, b1v.z)));
    m1.w = fmaxf(m1.w, leaky(fmaf(u1.w + v1.w, s1v.w, b1v.w)));
    m2.x = fmaxf(m2.x, leaky(fmaf(u2.x + v2.x, s2v.x, b2v.x)));
    m2.y = fmaxf(m2.y, leaky(fmaf(u2.y + v2.y, s2v.y, b2v.y)));
    m2.z = fmaxf(m2.z, leaky(fmaf(u2.z + v2.z, s2v.z, b2v.z)));
    m2.w = fmaxf(m2.w, leaky(fmaf(u2.w + v2.w, s2v.w, b2v.w)));
    m3.x = fmaxf(m3.x, leaky(fmaf(u3.x + v3.x, s3v.x, b3v.x)));
    m3.y = fmaxf(m3.y, leaky(fmaf(u3.y + v3.y, s3v.y, b3v.y)));
    m3.z = fmaxf(m3.z, leaky(fmaf(u3.z + v3.z, s3v.z, b3v.z)));
    m3.w = fmaxf(m3.w, leaky(fmaf(u3.w + v3.w, s3v.w, b3v.w)));
  }
  float* orow = outp + (size_t)g * 64 + cs;
  *(float4*)(orow + 0) = m0;
  *(float4*)(orow + 4) = m1;
  *(float4*)(orow + 8) = m2;
  *(float4*)(orow + 12) = m3;
}

// ---------------- generic tiled SGEMM: C = epi(A @ W^T) ----------------
#define AM_CAT3 0
#define AM_ROW 1
#define EPI_STORE 0
#define EPI_ADDG 1
#define EPI_MAX 2
#define EPI_RAW 3

template <int AMODE, int EPI, int BSUB>
__global__ __launch_bounds__(256) void gemmk(const float* __restrict__ a0, const float* __restrict__ a1,
                                             const float* __restrict__ a2, const float* __restrict__ w, int ldw,
                                             int Ksz, const float* __restrict__ sc, const float* __restrict__ bi,
                                             const float* __restrict__ gadd, float* __restrict__ outp, int ldo,
                                             unsigned* __restrict__ gmax) {
  __shared__ float As[16][68];
  __shared__ float Bs[16][68];
  int t = threadIdx.x, tx = t & 15, ty = t >> 4;
  int row0 = blockIdx.x * 64;
  int o0 = blockIdx.y * 64;
  float acc[4][4];
#pragma unroll
  for (int i = 0; i < 4; ++i)
#pragma unroll
    for (int j = 0; j < 4; ++j) acc[i][j] = 0.f;
  int arow = t >> 2;
  int ak4 = (t & 3) * 4;
  for (int k0 = 0; k0 < Ksz; k0 += 16) {
    __syncthreads();
    {
      int r = row0 + arow;
      int c = k0 + ak4;
      float4 v;
      if (AMODE == AM_CAT3) {
        const float* s = (c < 64) ? a0 : (c < 128 ? a1 : a2);
        v = *(const float4*)(s + (size_t)r * 64 + (c & 63));
      } else {
        v = *(const float4*)(a0 + (size_t)r * Ksz + c);
      }
      As[ak4 + 0][arow] = v.x;
      As[ak4 + 1][arow] = v.y;
      As[ak4 + 2][arow] = v.z;
      As[ak4 + 3][arow] = v.w;
      float4 wv = *(const float4*)(w + (size_t)(o0 + arow) * ldw + c);
      if (BSUB) {
        float4 w2v = *(const float4*)(w + (size_t)(o0 + arow) * ldw + Ksz + c);
        wv = make_float4(w2v.x - wv.x, w2v.y - wv.y, w2v.z - wv.z, w2v.w - wv.w);
      }
      Bs[ak4 + 0][arow] = wv.x;
      Bs[ak4 + 1][arow] = wv.y;
      Bs[ak4 + 2][arow] = wv.z;
      Bs[ak4 + 3][arow] = wv.w;
    }
    __syncthreads();
#pragma unroll
    for (int kk = 0; kk < 16; ++kk) {
      float4 a = *(const float4*)&As[kk][ty * 4];
      float4 bb = *(const float4*)&Bs[kk][tx * 4];
      acc[0][0] = fmaf(a.x, bb.x, acc[0][0]);
      acc[0][1] = fmaf(a.x, bb.y, acc[0][1]);
      acc[0][2] = fmaf(a.x, bb.z, acc[0][2]);
      acc[0][3] = fmaf(a.x, bb.w, acc[0][3]);
      acc[1][0] = fmaf(a.y, bb.x, acc[1][0]);
      acc[1][1] = fmaf(a.y, bb.y, acc[1][1]);
      acc[1][2] = fmaf(a.y, bb.z, acc[1][2]);
      acc[1][3] = fmaf(a.y, bb.w, acc[1][3]);
      acc[2][0] = fmaf(a.z, bb.x, acc[2][0]);
      acc[2][1] = fmaf(a.z, bb.y, acc[2][1]);
      acc[2][2] = fmaf(a.z, bb.z, acc[2][2]);
      acc[2][3] = fmaf(a.z, bb.w, acc[2][3]);
      acc[3][0] = fmaf(a.w, bb.x, acc[3][0]);
      acc[3][1] = fmaf(a.w, bb.y, acc[3][1]);
      acc[3][2] = fmaf(a.w, bb.z, acc[3][2]);
      acc[3][3] = fmaf(a.w, bb.w, acc[3][3]);
    }
  }
  float4 sv = make_float4(0.f, 0.f, 0.f, 0.f), bv = sv;
  if (EPI != EPI_RAW) {
    sv = *(const float4*)(sc + o0 + tx * 4);
    bv = *(const float4*)(bi + o0 + tx * 4);
  }
  if (EPI == EPI_MAX) {
    __syncthreads();
    float pm[4] = {-3.4e38f, -3.4e38f, -3.4e38f, -3.4e38f};
#pragma unroll
    for (int i = 0; i < 4; ++i) {
      pm[0] = fmaxf(pm[0], leaky(fmaf(acc[i][0], sv.x, bv.x)));
      pm[1] = fmaxf(pm[1], leaky(fmaf(acc[i][1], sv.y, bv.y)));
      pm[2] = fmaxf(pm[2], leaky(fmaf(acc[i][2], sv.z, bv.z)));
      pm[3] = fmaxf(pm[3], leaky(fmaf(acc[i][3], sv.w, bv.w)));
    }
    As[ty][tx * 4 + 0] = pm[0];
    As[ty][tx * 4 + 1] = pm[1];
    As[ty][tx * 4 + 2] = pm[2];
    As[ty][tx * 4 + 3] = pm[3];
    __syncthreads();
    if (t < 64) {
      float m = As[0][t];
#pragma unroll
      for (int g = 1; g < 16; ++g) m = fmaxf(m, As[g][t]);
      int b = row0 >> 12;
      atomicMax(&gmax[b * 1024 + o0 + t], encf(m));
    }
  } else if (EPI == EPI_RAW) {
#pragma unroll
    for (int i = 0; i < 4; ++i) {
      int r = row0 + ty * 4 + i;
      float4 ov = make_float4(acc[i][0], acc[i][1], acc[i][2], acc[i][3]);
      *(float4*)(outp + (size_t)r * ldo + o0 + tx * 4) = ov;
    }
  } else {
    float4 ga = make_float4(0.f, 0.f, 0.f, 0.f);
    if (EPI == EPI_ADDG) ga = *(const float4*)(gadd + (row0 >> 12) * 256 + o0 + tx * 4);
#pragma unroll
    for (int i = 0; i < 4; ++i) {
      int r = row0 + ty * 4 + i;
      float4 ov;
      ov.x = leaky(fmaf(acc[i][0] + ga.x, sv.x, bv.x));
      ov.y = leaky(fmaf(acc[i][1] + ga.y, sv.y, bv.y));
      ov.z = leaky(fmaf(acc[i][2] + ga.z, sv.z, bv.z));
      ov.w = leaky(fmaf(acc[i][3] + ga.w, sv.w, bv.w));
      *(float4*)(outp + (size_t)r * ldo + o0 + tx * 4) = ov;
    }
  }
}

// ---------------- per-batch g . w8[:, :1024] ----------------
__global__ __launch_bounds__(256) void gdotk(const unsigned* __restrict__ gmax, const float* __restrict__ w8,
                                             float* __restrict__ gb8) {
  int wv = blockIdx.x * 4 + (threadIdx.x >> 6);
  int lane = threadIdx.x & 63;
  int b = wv >> 8, o = wv & 255;
  const float* wr = w8 + (size_t)o * 1216;
  const unsigned* gr = gmax + b * 1024;
  float acc = 0.f;
#pragma unroll
  for (int l = 0; l < 4; ++l) {
    int c = lane * 4 + l * 256;
    float4 wv4 = *(const float4*)(wr + c);
    acc = fmaf(decf(gr[c + 0]), wv4.x, acc);
    acc = fmaf(decf(gr[c + 1]), wv4.y, acc);
    acc = fmaf(decf(gr[c + 2]), wv4.z, acc);
    acc = fmaf(decf(gr[c + 3]), wv4.w, acc);
  }
#pragma unroll
  for (int off = 32; off >= 1; off >>= 1) acc += __shfl_down(acc, off);
  if (lane == 0) gb8[b * 256 + o] = acc;
}

// ---------------- final 128 -> 13 projection + transpose ----------------
__global__ __launch_bounds__(256) void outk(const float* __restrict__ h10, const float* __restrict__ w11,
                                            float* __restrict__ outp) {
  __shared__ float hs[64][132];
  __shared__ float wsm[13][128];
  int b = blockIdx.y, n0 = blockIdx.x * 64, t = threadIdx.x;
  for (int e = t; e < 13 * 128; e += 256) wsm[e >> 7][e & 127] = w11[e];
  const float* hb = h10 + ((size_t)(b * NPTS + n0)) * 128;
#pragma unroll
  for (int l = 0; l < 8; ++l) {
    int v = t + l * 256;
    int row = v >> 5, c4 = (v & 31) * 4;
    *(float4*)(&hs[row][c4]) = *(const float4*)(hb + (size_t)row * 128 + c4);
  }
  __syncthreads();
  for (int e = t; e < 13 * 64; e += 256) {
    int o = e >> 6, n = e & 63;
    float a0 = 0, a1 = 0, a2 = 0, a3 = 0;
#pragma unroll
    for (int c4 = 0; c4 < 32; ++c4) {
      float4 hv = *(const float4*)(&hs[n][c4 * 4]);
      const float* wr = &wsm[o][c4 * 4];
      a0 = fmaf(hv.x, wr[0], a0);
      a1 = fmaf(hv.y, wr[1], a1);
      a2 = fmaf(hv.z, wr[2], a2);
      a3 = fmaf(hv.w, wr[3], a3);
    }
    outp[((size_t)b * 13 + o) * NPTS + n0 + n] = (a0 + a1) + (a2 + a3);
  }
}

extern "C" void kernel_launch(void* const* d_in, const int* in_sizes, int n_in, void* d_out, int out_size, void* d_ws,
                              size_t ws_size, hipStream_t stream) {
  (void)in_sizes;
  (void)n_in;
  (void)out_size;
  (void)ws_size;
  const float* x = (const float*)d_in[0];
  const float* w1 = (const float*)d_in[1];
  const float* s1 = (const float*)d_in[2];
  const float* b1 = (const float*)d_in[3];
  const float* w2 = (const float*)d_in[4];
  const float* s2 = (const float*)d_in[5];
  const float* b2 = (const float*)d_in[6];
  const float* w3 = (const float*)d_in[7];
  const float* s3 = (const float*)d_in[8];
  const float* b3 = (const float*)d_in[9];
  const float* w4 = (const float*)d_in[10];
  const float* s4 = (const float*)d_in[11];
  const float* b4 = (const float*)d_in[12];
  const float* w5 = (const float*)d_in[13];
  const float* s5 = (const float*)d_in[14];
  const float* b5 = (const float*)d_in[15];
  const float* w6 = (const float*)d_in[16];
  const float* s6 = (const float*)d_in[17];
  const float* b6 = (const float*)d_in[18];
  const float* w8 = (const float*)d_in[19];
  const float* s8 = (const float*)d_in[20];
  const float* b8 = (const float*)d_in[21];
  const float* w9 = (const float*)d_in[22];
  const float* s9 = (const float*)d_in[23];
  const float* b9 = (const float*)d_in[24];
  const float* w10 = (const float*)d_in[25];
  const float* s10 = (const float*)d_in[26];
  const float* b10 = (const float*)d_in[27];
  const float* w11 = (const float*)d_in[28];

  float* ws = (float*)d_ws;
  size_t off = 0;
  int* idxb = (int*)ws;
  off += 655360;  // B*N*20
  float* x1 = ws + off;
  off += 2097152;
  float* x2 = ws + off;
  off += 2097152;
  float* x3 = ws + off;
  off += 2097152;
  float* nrm = ws + off;
  off += 131072;
  unsigned* gmax = (unsigned*)(ws + off);
  off += 8192;
  float* gb8 = ws + off;
  off += 2048;
  float* h8 = ws + off;
  off += 8388608;
  float* h9 = ws + off;
  off += 8388608;
  float* h10 = h8;        // reuse (h8 dead after l9)
  float* U = h9;          // U/V live only before w9 GEMM
  float* V = h9 + 2097152;
  float* outp = (float*)d_out;

  knn_c3<<<dim3(64, BATCH), 256, 0, stream>>>(x, idxb);
  uv3<<<dim3(512), 256, 0, stream>>>(x, w1, U, V);
  edgemax2<<<dim3(4096), 256, 0, stream>>>(U, V, idxb, s1, b1, w2, s2, b2, x1);
  rownormk<<<dim3(128), 256, 0, stream>>>(x1, nrm);
  knn64g<<<dim3(64, BATCH), 128, 0, stream>>>(x1, nrm, idxb);
  gemmk<AM_ROW, EPI_RAW, 0><<<dim3(512, 1), 256, 0, stream>>>(x1, nullptr, nullptr, w3, 128, 64, nullptr, nullptr,
                                                              nullptr, U, 64, nullptr);
  gemmk<AM_ROW, EPI_RAW, 1><<<dim3(512, 1), 256, 0, stream>>>(x1, nullptr, nullptr, w3, 128, 64, nullptr, nullptr,
                                                              nullptr, V, 64, nullptr);
  edgemax2<<<dim3(4096), 256, 0, stream>>>(U, V, idxb, s3, b3, w4, s4, b4, x2);
  rownormk<<<dim3(128), 256, 0, stream>>>(x2, nrm);
  knn64g<<<dim3(64, BATCH), 128, 0, stream>>>(x2, nrm, idxb);
  gemmk<AM_ROW, EPI_RAW, 0><<<dim3(512, 1), 256, 0, stream>>>(x2, nullptr, nullptr, w5, 128, 64, nullptr, nullptr,
                                                              nullptr, U, 64, nullptr);
  gemmk<AM_ROW, EPI_RAW, 1><<<dim3(512, 1), 256, 0, stream>>>(x2, nullptr, nullptr, w5, 128, 64, nullptr, nullptr,
                                                              nullptr, V, 64, nullptr);
  edgemax1<<<dim3(512), 256, 0, stream>>>(U, V, idxb, s5, b5, x3);
  hipMemsetAsync(gmax, 0, 8192 * sizeof(unsigned), stream);
  gemmk<AM_CAT3, EPI_MAX, 0><<<dim3(512, 16), 256, 0, stream>>>(x1, x2, x3, w6, 192, 192, s6, b6, nullptr, nullptr, 0,
                                                                gmax);
  gdotk<<<dim3(512), 256, 0, stream>>>(gmax, w8, gb8);
  gemmk<AM_CAT3, EPI_ADDG, 0><<<dim3(512, 4), 256, 0, stream>>>(x1, x2, x3, w8 + 1024, 1216, 192, s8, b8, gb8, h8, 256,
                                                                nullptr);
  gemmk<AM_ROW, EPI_STORE, 0><<<dim3(512, 4), 256, 0, stream>>>(h8, nullptr, nullptr, w9, 256, 256, s9, b9, nullptr,
                                                                h9, 256, nullptr);
  gemmk<AM_ROW, EPI_STORE, 0><<<dim3(512, 2), 256, 0, stream>>>(h9, nullptr, nullptr, w10, 256, 256, s10, b10, nullptr,
                                                                h10, 128, nullptr);
  outk<<<dim3(64, BATCH), 256, 0, stream>>>(h10, w11, outp);
}